// Round 12
// baseline (2261.389 us; speedup 1.0000x reference)
//
#include <hip/hip_runtime.h>
#include <hip/hip_fp16.h>

#define TENC 64
#define TDEC 18
#define NDEC 24
#define NF1  17
#define NF2  129
#define HH   128

// ---- ws layout ----
#define OFF_WI   0        // [16][64] float4
#define OFF_WI2  4096     // [16][64] float4
#define U_GB   8192      // [73][512]  phase B gate pairs (x 0..8 | h 9..72)
#define U_GDH  45568     // [64][512]  phase D h-part (pairs 65..128)
#define U_GDX  78336     // [65][512]  phase D x-part (pairs 0..64)
#define U_GFH  111616    // [64][512]  phase F h-part (pairs 64..127)
#define U_GFX  144384    // [64][512]  phase F din-part (pairs 0..63)
#define U_WE   177152    // [64][128]  We   (pr = i*8+pq)
#define U_WE2  185344    // [64][128]  We2
#define U_WH   193536    // [128][128] Wh   (pr = i*4+pq)
#define U_WXH  209920    // [64][128]  Wx f16 pairs

#define SB   68
#define SWF  132
#define XIN  1200
#define BIGN 8772

typedef _Float16 h2t __attribute__((ext_vector_type(2)));

#if defined(__has_builtin)
#if __has_builtin(__builtin_amdgcn_fdot2)
#define HAVE_FDOT2 1
#endif
#endif

template<int I> struct ic_t { static constexpr int v = I; };
template<int N, typename F>
__device__ __forceinline__ void sfor(F&& f)
{
    if constexpr (N > 0) { sfor<N - 1>((F&&)f); f(ic_t<N - 1>{}); }
}

__device__ __forceinline__ float fdot2p(unsigned w, unsigned x, float acc)
{
    h2t hw = __builtin_bit_cast(h2t, w);
    h2t hx = __builtin_bit_cast(h2t, x);
#ifdef HAVE_FDOT2
    return __builtin_amdgcn_fdot2(hw, hx, acc, false);
#else
    return acc + (float)hw.x * (float)hx.x + (float)hw.y * (float)hx.y;
#endif
}

__device__ __forceinline__ unsigned pkh_d(float a, float b)
{
    __half ha = __float2half(a), hb = __float2half(b);
    return (unsigned)__half_as_ushort(ha) | ((unsigned)__half_as_ushort(hb) << 16);
}

__device__ __forceinline__ float hget(unsigned u, int hi)
{
    h2t v = __builtin_bit_cast(h2t, u);
    return hi ? (float)v.y : (float)v.x;
}

__device__ __forceinline__ float fsig(float x) { return 1.f / (1.f + __expf(-x)); }
__device__ __forceinline__ float ftanh(float x)
{
    x = fminf(fmaxf(x, -15.f), 15.f);
    float e = __expf(2.f * x);
    return (e - 1.f) / (e + 1.f);
}

// ---------------- pack kernels ----------------
__global__ void pack_f2(const float* Wi, const float* Wi2, float* ws)
{
    const int m = blockIdx.y;
    const float* src = m ? Wi2 : Wi;
    const int off = m ? OFF_WI2 : OFF_WI;
    const int G = 64, K = 64, n = G * K;
    for (int i = blockIdx.x * blockDim.x + threadIdx.x; i < n; i += gridDim.x * blockDim.x) {
        int q = i & 3, gk = i >> 2;
        int kk = gk / G, g = gk - kk * G;
        ws[off + i] = src[g * K + kk * 4 + q];
    }
}

__global__ void pack_gp(const float* Wih, const float* Whh, int Kx, int KXP, int qbase,
                        unsigned base, int ldg, unsigned* wsu)
{
    const int g = threadIdx.x;
    const int q = qbase + blockIdx.x;
    int k0 = 2 * q, k1 = 2 * q + 1;
    float f0 = (k0 < KXP) ? ((k0 < Kx) ? Wih[g * Kx + k0] : 0.f) : Whh[g * HH + (k0 - KXP)];
    float f1 = (k1 < KXP) ? ((k1 < Kx) ? Wih[g * Kx + k1] : 0.f) : Whh[g * HH + (k1 - KXP)];
    wsu[base + (unsigned)blockIdx.x * (unsigned)ldg + g] = pkh_d(f0, f1);
}

__global__ void pack_ew(const float* W, int J, int nPQ, int nI, unsigned base, unsigned* wsu)
{
    int idx = blockIdx.x * blockDim.x + threadIdx.x;
    if (idx >= J * 128) return;
    int j = idx >> 7, r = idx & 127;
    int pq = r / nI, i = r - pq * nI;
    int pr = i * nPQ + pq;
    wsu[base + idx] = pkh_d(W[j * 256 + 2 * pr], W[j * 256 + 2 * pr + 1]);
}

// ---------------- main kernel: 512 threads, 2 batch elems/WG, grid 256 ----------------
// gates_h hoisted into the score block: independent fdot2 stream fills the
// exp/rcp (trans-pipe) latency shadows; post-softmax gate block is x-part only.
__global__ __launch_bounds__(512, 2)
void dstp_main(const float* __restrict__ inq, const float* __restrict__ labp,
               const float* __restrict__ bih1, const float* __restrict__ bhh1,
               const float* __restrict__ bih2, const float* __restrict__ bhh2,
               const float* __restrict__ bihd, const float* __restrict__ bhhd,
               const float* __restrict__ Wi_b, const float* __restrict__ Vd_w, const float* __restrict__ Vd_b,
               const float* __restrict__ Wi2_b, const float* __restrict__ Vd2_w, const float* __restrict__ Vd2_b,
               const float* __restrict__ Wx_b, const float* __restrict__ V_w, const float* __restrict__ V_b,
               const float* __restrict__ reg_w, const float* __restrict__ reg_b,
               const float* __restrict__ ws, float* __restrict__ out)
{
    __shared__ __align__(16) unsigned buf_h[2][TENC][64];   // mid/final h as f16 pairs
    __shared__ __align__(16) float big[2][BIGN];            // WiX+xin / Wi2X / WxF
    __shared__ __align__(16) unsigned hcp[2][128];          // f16 pairs: h 0..63 | c 64..127
    __shared__ __align__(16) unsigned xhp[2][132];          // broadcast pairs (x/din parts)
    __shared__ __align__(16) float ebuf[2][128];
    __shared__ float sc[2][132];
    __shared__ float att[2][64];
    __shared__ float pre[2][512];
    __shared__ float lab[2][64];
    __shared__ __align__(16) float vw1[64], vw2[64], vwf[128], rw[128];
    __shared__ float rsm[4];

    const int tid  = threadIdx.x;
    const int b0   = blockIdx.x * 2;
    const unsigned* wsu = (const unsigned*)ws;
    const float4* Wip  = (const float4*)(ws + OFF_WI);
    const float4* Wi2p = (const float4*)(ws + OFF_WI2);

    const float bg1 = bih1[tid] + bhh1[tid];
    const float bg2 = bih2[tid] + bhh2[tid];
    const float bgd = bihd[tid] + bhhd[tid];
    float creg = 0.f;   // fp32 cell state (pointwise thread tid<256, per bb)

    // ================= Phase A: inputs, WiX =================
    if (tid < 128) lab[tid >> 6][tid & 63] = labp[(b0 + (tid >> 6)) * TENC + (tid & 63)];
    if (tid < 64)        vw1[tid]       = Vd_w[tid];
    else if (tid < 128)  vw2[tid - 64]  = Vd2_w[tid - 64];
    else if (tid < 256)  vwf[tid - 128] = V_w[tid - 128];
    else if (tid < 384)  rw[tid - 256]  = reg_w[tid - 256];
    for (int i = tid; i < 2176; i += 512) {           // xin: x[t][f], COLS skip 14
        int bb = i / 1088, r = i - bb * 1088, t = r / NF1, f = r - t * NF1;
        big[bb][XIN + r] = inq[((b0 + bb) * TENC + t) * 18 + f + (f >= 14)];
    }
    __syncthreads();
    for (int i = tid; i < 2176; i += 512) {           // WiX[f][j]
        int bb = i / 1088, r = i - bb * 1088, f = r >> 6, j = r & 63;
        float acc = Wi_b[j];
        for (int tt = 0; tt < 16; ++tt) {
            float4 w = Wip[tt * 64 + j];
            acc += big[bb][XIN + (4 * tt + 0) * NF1 + f] * w.x
                 + big[bb][XIN + (4 * tt + 1) * NF1 + f] * w.y
                 + big[bb][XIN + (4 * tt + 2) * NF1 + f] * w.z
                 + big[bb][XIN + (4 * tt + 3) * NF1 + f] * w.w;
        }
        big[bb][f * SB + j] = acc;
    }

    // ================= Phase B: encoder scan 1 =================
    {
        if (tid < 256) hcp[tid >> 7][tid & 127] = 0u;
        if (tid < 264) xhp[tid / 132][tid % 132] = 0u;
        creg = 0.f;
        unsigned wB[73];
        sfor<73>([&](auto I) { wB[I.v] = wsu[U_GB + I.v * 512 + tid]; });
        unsigned we[16];
        const int ewb = U_WE + ((tid >> 3) << 7) + ((tid & 7) << 4);
        sfor<16>([&](auto I) { we[I.v] = wsu[ewb + I.v]; });
        __syncthreads();

        for (int t = 0; t < TENC; ++t) {
            {   // e[j] for both elems, 2 chains/elem
                int j = tid >> 3, pq = tid & 7;
                float a0 = 0.f, a1 = 0.f, b0c = 0.f, b1c = 0.f;
                sfor<8>([&](auto I) {
                    a0  = fdot2p(we[I.v], hcp[0][I.v * 8 + pq], a0);
                    a1  = fdot2p(we[I.v], hcp[1][I.v * 8 + pq], a1);
                    b0c = fdot2p(we[8 + I.v], hcp[0][(8 + I.v) * 8 + pq], b0c);
                    b1c = fdot2p(we[8 + I.v], hcp[1][(8 + I.v) * 8 + pq], b1c);
                });
                float s0 = a0 + b0c, s1 = a1 + b1c;
                s0 += __shfl_xor(s0, 1, 8); s1 += __shfl_xor(s1, 1, 8);
                s0 += __shfl_xor(s0, 2, 8); s1 += __shfl_xor(s1, 2, 8);
                s0 += __shfl_xor(s0, 4, 8); s1 += __shfl_xor(s1, 4, 8);
                if (pq == 0) { ebuf[0][j] = s0; ebuf[1][j] = s1; }
            }
            __syncthreads();
            // ---- block1: score + gates_h (interleaved trans/fdot2) ----
            float q00 = 0.f, q01 = 0.f, q10 = 0.f, q11 = 0.f;   // gates_h partials
            {
                const uint4* h0q = (const uint4*)hcp[0];
                const uint4* h1q = (const uint4*)hcp[1];
                sfor<16>([&](auto C) {
                    uint4 H0 = h0q[C.v], H1 = h1q[C.v];
                    q00 = fdot2p(wB[9 + 4 * C.v + 0], H0.x, q00);
                    q10 = fdot2p(wB[9 + 4 * C.v + 0], H1.x, q10);
                    q01 = fdot2p(wB[9 + 4 * C.v + 1], H0.y, q01);
                    q11 = fdot2p(wB[9 + 4 * C.v + 1], H1.y, q11);
                    q00 = fdot2p(wB[9 + 4 * C.v + 2], H0.z, q00);
                    q10 = fdot2p(wB[9 + 4 * C.v + 2], H1.z, q10);
                    q01 = fdot2p(wB[9 + 4 * C.v + 3], H0.w, q01);
                    q11 = fdot2p(wB[9 + 4 * C.v + 3], H1.w, q11);
                });
            }
            for (int i = tid; i < 544; i += 512) {   // score[f]: 16 threads per (bb,f)
                int bb = i / 272, r = i - bb * 272, f = r >> 4, pp = r & 15;
                float4 wx = *(const float4*)&big[bb][f * SB + pp * 4];
                float4 e4 = *(const float4*)&ebuf[bb][pp * 4];
                float4 v4 = *(const float4*)&vw1[pp * 4];
                float acc = ftanh(wx.x + e4.x) * v4.x + ftanh(wx.y + e4.y) * v4.y
                          + ftanh(wx.z + e4.z) * v4.z + ftanh(wx.w + e4.w) * v4.w;
                acc += __shfl_xor(acc, 1, 16);
                acc += __shfl_xor(acc, 2, 16);
                acc += __shfl_xor(acc, 4, 16);
                acc += __shfl_xor(acc, 8, 16);
                if (pp == 0) sc[bb][f] = acc + Vd_b[0];
            }
            __syncthreads();
            if (tid < 128) {   // softmax(17) + pack x pairs 0..8
                int bb = tid >> 6, l = tid & 63;
                float v = (l < NF1) ? sc[bb][l] : -1e30f;
                float m = v;
                for (int d = 32; d; d >>= 1) m = fmaxf(m, __shfl_xor(m, d, 64));
                float e = (l < NF1) ? __expf(v - m) : 0.f;
                float s = e;
                for (int d = 32; d; d >>= 1) s += __shfl_xor(s, d, 64);
                float xv = (l < NF1) ? big[bb][XIN + t * NF1 + l] * (e / s) : 0.f;
                float xp = __shfl_xor(xv, 1, 64);
                if (!(l & 1) && l < 18) xhp[bb][l >> 1] = pkh_d(xv, xp);
            }
            __syncthreads();
            {   // block2: gates_x (pairs 0..8) + combine
                const uint4* x0q = (const uint4*)xhp[0];
                const uint4* x1q = (const uint4*)xhp[1];
                float p00 = bg1, p10 = bg1;
                sfor<2>([&](auto C) {
                    uint4 X0 = x0q[C.v], X1 = x1q[C.v];
                    p00 = fdot2p(wB[4 * C.v + 0], X0.x, p00);
                    p10 = fdot2p(wB[4 * C.v + 0], X1.x, p10);
                    q00 = fdot2p(wB[4 * C.v + 1], X0.y, q00);
                    q10 = fdot2p(wB[4 * C.v + 1], X1.y, q10);
                    p00 = fdot2p(wB[4 * C.v + 2], X0.z, p00);
                    p10 = fdot2p(wB[4 * C.v + 2], X1.z, p10);
                    q00 = fdot2p(wB[4 * C.v + 3], X0.w, q00);
                    q10 = fdot2p(wB[4 * C.v + 3], X1.w, q10);
                });
                p00 = fdot2p(wB[8], xhp[0][8], p00);
                p10 = fdot2p(wB[8], xhp[1][8], p10);
                pre[0][tid] = (p00 + q00) + q01;
                pre[1][tid] = (p10 + q10) + q11;
            }
            __syncthreads();
            if (tid < 256) {   // LSTM pointwise
                int bb = tid >> 7, k = tid & 127;
                float gi = pre[bb][k], gf = pre[bb][128 + k], gg = pre[bb][256 + k], go = pre[bb][384 + k];
                float c2 = fsig(gf) * creg + fsig(gi) * ftanh(gg);
                float h2v = fsig(go) * ftanh(c2);
                creg = c2;
                float hp = __shfl_xor(h2v, 1, 64);
                float cp = __shfl_xor(c2, 1, 64);
                if (!(k & 1)) {
                    unsigned hu = pkh_d(h2v, hp);
                    hcp[bb][k >> 1] = hu;
                    hcp[bb][64 + (k >> 1)] = pkh_d(c2, cp);
                    buf_h[bb][t][k >> 1] = hu;    // mid as f16 pair
                }
            }
            __syncthreads();
        }
    }

    // ================= Phase C: Wi2X (reads f16 mid) =================
    if (tid < 256) hcp[tid >> 7][tid & 127] = 0u;
    if (tid < 264) xhp[tid / 132][tid % 132] = 0u;
    creg = 0.f;
    for (int i = tid; i < 16512; i += 512) {
        int bb = i / 8256, r = i - bb * 8256, f = r >> 6, j = r & 63;
        float acc = Wi2_b[j];
        if (f < HH) {
            int fp = f >> 1, fh = f & 1;
            for (int tt = 0; tt < 16; ++tt) {
                float4 w = Wi2p[tt * 64 + j];
                acc += hget(buf_h[bb][4 * tt + 0][fp], fh) * w.x
                     + hget(buf_h[bb][4 * tt + 1][fp], fh) * w.y
                     + hget(buf_h[bb][4 * tt + 2][fp], fh) * w.z
                     + hget(buf_h[bb][4 * tt + 3][fp], fh) * w.w;
            }
        } else {
            for (int tt = 0; tt < 16; ++tt) {
                float4 w = Wi2p[tt * 64 + j];
                acc += lab[bb][4 * tt] * w.x + lab[bb][4 * tt + 1] * w.y
                     + lab[bb][4 * tt + 2] * w.z + lab[bb][4 * tt + 3] * w.w;
            }
        }
        big[bb][f * SB + j] = acc;
    }

    // ================= Phase D: encoder scan 2 =================
    {
        unsigned wD[129];   // pairs 0..64 = x part, 65..128 = h part
        sfor<65>([&](auto I) { wD[I.v] = wsu[U_GDX + I.v * 512 + tid]; });
        sfor<64>([&](auto I) { wD[65 + I.v] = wsu[U_GDH + I.v * 512 + tid]; });
        unsigned wes[16];
        const int ewb2 = U_WE2 + ((tid >> 3) << 7) + ((tid & 7) << 4);
        sfor<16>([&](auto I) { wes[I.v] = wsu[ewb2 + I.v]; });
        __syncthreads();

        for (int t = 0; t < TENC; ++t) {
            {   // e[j] both elems, 2 chains/elem
                int j = tid >> 3, pq = tid & 7;
                float a0 = 0.f, a1 = 0.f, b0c = 0.f, b1c = 0.f;
                sfor<8>([&](auto I) {
                    a0  = fdot2p(wes[I.v], hcp[0][I.v * 8 + pq], a0);
                    a1  = fdot2p(wes[I.v], hcp[1][I.v * 8 + pq], a1);
                    b0c = fdot2p(wes[8 + I.v], hcp[0][(8 + I.v) * 8 + pq], b0c);
                    b1c = fdot2p(wes[8 + I.v], hcp[1][(8 + I.v) * 8 + pq], b1c);
                });
                float s0 = a0 + b0c, s1 = a1 + b1c;
                s0 += __shfl_xor(s0, 1, 8); s1 += __shfl_xor(s1, 1, 8);
                s0 += __shfl_xor(s0, 2, 8); s1 += __shfl_xor(s1, 2, 8);
                s0 += __shfl_xor(s0, 4, 8); s1 += __shfl_xor(s1, 4, 8);
                if (pq == 0) { ebuf[0][j] = s0; ebuf[1][j] = s1; }
            }
            __syncthreads();
            // ---- block1: score + gates_h ----
            float q00 = 0.f, q01 = 0.f, q10 = 0.f, q11 = 0.f;
            {
                const uint4* h0q = (const uint4*)hcp[0];
                const uint4* h1q = (const uint4*)hcp[1];
                sfor<16>([&](auto C) {
                    uint4 H0 = h0q[C.v], H1 = h1q[C.v];
                    q00 = fdot2p(wD[65 + 4 * C.v + 0], H0.x, q00);
                    q10 = fdot2p(wD[65 + 4 * C.v + 0], H1.x, q10);
                    q01 = fdot2p(wD[65 + 4 * C.v + 1], H0.y, q01);
                    q11 = fdot2p(wD[65 + 4 * C.v + 1], H1.y, q11);
                    q00 = fdot2p(wD[65 + 4 * C.v + 2], H0.z, q00);
                    q10 = fdot2p(wD[65 + 4 * C.v + 2], H1.z, q10);
                    q01 = fdot2p(wD[65 + 4 * C.v + 3], H0.w, q01);
                    q11 = fdot2p(wD[65 + 4 * C.v + 3], H1.w, q11);
                });
            }
            for (int i = tid; i < 1032; i += 512) {   // score[f]: 4 threads per (bb,f)
                int bb = i / 516, r = i - bb * 516, f = r >> 2, pp = r & 3;
                float acc = 0.f;
                #pragma unroll
                for (int c = 0; c < 4; ++c) {
                    float4 wx = *(const float4*)&big[bb][f * SB + pp * 16 + c * 4];
                    float4 e4 = *(const float4*)&ebuf[bb][pp * 16 + c * 4];
                    float4 v4 = *(const float4*)&vw2[pp * 16 + c * 4];
                    acc += ftanh(wx.x + e4.x) * v4.x + ftanh(wx.y + e4.y) * v4.y
                         + ftanh(wx.z + e4.z) * v4.z + ftanh(wx.w + e4.w) * v4.w;
                }
                acc += __shfl_xor(acc, 1, 4);
                acc += __shfl_xor(acc, 2, 4);
                if (pp == 0) sc[bb][f] = acc + Vd2_b[0];
            }
            __syncthreads();
            if (tid < 128) {   // softmax(129) + pack x pairs 0..64
                int bb = tid >> 6, l = tid & 63;
                float s1 = sc[bb][l], s2 = sc[bb][l + 64];
                float s3 = (l == 0) ? sc[bb][128] : -1e30f;
                float m = fmaxf(fmaxf(s1, s2), s3);
                for (int d = 32; d; d >>= 1) m = fmaxf(m, __shfl_xor(m, d, 64));
                float e1 = __expf(s1 - m), e2 = __expf(s2 - m);
                float e3 = (l == 0) ? __expf(s3 - m) : 0.f;
                float s = e1 + e2 + e3;
                for (int d = 32; d; d >>= 1) s += __shfl_xor(s, d, 64);
                float inv = 1.f / s;
                float v1 = hget(buf_h[bb][t][l >> 1], l & 1) * e1 * inv;
                float v2 = hget(buf_h[bb][t][32 + (l >> 1)], l & 1) * e2 * inv;
                float v1p = __shfl_xor(v1, 1, 64);
                float v2p = __shfl_xor(v2, 1, 64);
                if (!(l & 1)) {
                    xhp[bb][l >> 1] = pkh_d(v1, v1p);
                    xhp[bb][32 + (l >> 1)] = pkh_d(v2, v2p);
                }
                if (l == 0) xhp[bb][64] = pkh_d(lab[bb][t] * e3 * inv, 0.f);
            }
            __syncthreads();
            {   // block2: gates_x (pairs 0..64) + combine
                const uint4* x0q = (const uint4*)xhp[0];
                const uint4* x1q = (const uint4*)xhp[1];
                float p00 = bg2, p01 = 0.f, p10 = bg2, p11 = 0.f;
                sfor<16>([&](auto C) {
                    uint4 X0 = x0q[C.v], X1 = x1q[C.v];
                    p00 = fdot2p(wD[4 * C.v + 0], X0.x, p00);
                    p10 = fdot2p(wD[4 * C.v + 0], X1.x, p10);
                    p01 = fdot2p(wD[4 * C.v + 1], X0.y, p01);
                    p11 = fdot2p(wD[4 * C.v + 1], X1.y, p11);
                    p00 = fdot2p(wD[4 * C.v + 2], X0.z, p00);
                    p10 = fdot2p(wD[4 * C.v + 2], X1.z, p10);
                    p01 = fdot2p(wD[4 * C.v + 3], X0.w, p01);
                    p11 = fdot2p(wD[4 * C.v + 3], X1.w, p11);
                });
                p00 = fdot2p(wD[64], xhp[0][64], p00);
                p10 = fdot2p(wD[64], xhp[1][64], p10);
                pre[0][tid] = (p00 + p01) + (q00 + q01);
                pre[1][tid] = (p10 + p11) + (q10 + q11);
            }
            __syncthreads();
            if (tid < 256) {
                int bb = tid >> 7, k = tid & 127;
                float gi = pre[bb][k], gf = pre[bb][128 + k], gg = pre[bb][256 + k], go = pre[bb][384 + k];
                float c2 = fsig(gf) * creg + fsig(gi) * ftanh(gg);
                float h2v = fsig(go) * ftanh(c2);
                creg = c2;
                float hp = __shfl_xor(h2v, 1, 64);
                float cp = __shfl_xor(c2, 1, 64);
                if (!(k & 1)) {
                    unsigned hu = pkh_d(h2v, hp);
                    hcp[bb][k >> 1] = hu;
                    hcp[bb][64 + (k >> 1)] = pkh_d(c2, cp);
                    buf_h[bb][t][k >> 1] = hu;    // final overwrites consumed mid row
                }
            }
            __syncthreads();
        }
    }

    // ================= Phase E: WxF via f16 fdot2 (b128 broadcast reads) =================
    if (tid < 256) hcp[tid >> 7][tid & 127] = 0u;
    if (tid < 264) xhp[tid / 132][tid % 132] = 0u;
    creg = 0.f;
    {
        const int j = tid & 127;
        unsigned wxh[64];
        sfor<64>([&](auto I) { wxh[I.v] = wsu[U_WXH + I.v * 128 + j]; });
        for (int u = tid >> 7; u < 128; u += 4) {
            int bb = u >> 6, tt = u & 63;
            const uint4* bq = (const uint4*)buf_h[bb][tt];
            float a0 = Wx_b[j], a1 = 0.f, a2 = 0.f, a3 = 0.f;
            sfor<16>([&](auto C) {
                uint4 X = bq[C.v];
                a0 = fdot2p(wxh[4 * C.v + 0], X.x, a0);
                a1 = fdot2p(wxh[4 * C.v + 1], X.y, a1);
                a2 = fdot2p(wxh[4 * C.v + 2], X.z, a2);
                a3 = fdot2p(wxh[4 * C.v + 3], X.w, a3);
            });
            big[bb][tt * SWF + j] = (a0 + a1) + (a2 + a3);
        }
    }

    // ================= Phase F: decoder =================
    {
        unsigned wF[128];   // pairs 0..63 = din part, 64..127 = h part
        sfor<64>([&](auto I) { wF[I.v] = wsu[U_GFX + I.v * 512 + tid]; });
        sfor<64>([&](auto I) { wF[64 + I.v] = wsu[U_GFH + I.v * 512 + tid]; });
        unsigned wh[32];
        const int whb = U_WH + ((tid >> 2) << 7) + ((tid & 3) << 5);
        sfor<32>([&](auto I) { wh[I.v] = wsu[whb + I.v]; });
        __syncthreads();

        for (int n = 0; n < NDEC; ++n) {
            {   // e[j] both elems, 2 chains/elem
                int j = tid >> 2, pq = tid & 3;
                float a0 = 0.f, a1 = 0.f, b0c = 0.f, b1c = 0.f;
                sfor<16>([&](auto I) {
                    a0  = fdot2p(wh[I.v], hcp[0][I.v * 4 + pq], a0);
                    a1  = fdot2p(wh[I.v], hcp[1][I.v * 4 + pq], a1);
                    b0c = fdot2p(wh[16 + I.v], hcp[0][(16 + I.v) * 4 + pq], b0c);
                    b1c = fdot2p(wh[16 + I.v], hcp[1][(16 + I.v) * 4 + pq], b1c);
                });
                float s0 = a0 + b0c, s1 = a1 + b1c;
                s0 += __shfl_xor(s0, 1, 4); s1 += __shfl_xor(s1, 1, 4);
                s0 += __shfl_xor(s0, 2, 4); s1 += __shfl_xor(s1, 2, 4);
                if (pq == 0) { ebuf[0][j] = s0; ebuf[1][j] = s1; }
            }
            __syncthreads();
            // ---- block1: s[tt] + gates_h ----
            float q00 = 0.f, q01 = 0.f, q10 = 0.f, q11 = 0.f;
            {
                const uint4* h0q = (const uint4*)hcp[0];
                const uint4* h1q = (const uint4*)hcp[1];
                sfor<16>([&](auto C) {
                    uint4 H0 = h0q[C.v], H1 = h1q[C.v];
                    q00 = fdot2p(wF[64 + 4 * C.v + 0], H0.x, q00);
                    q10 = fdot2p(wF[64 + 4 * C.v + 0], H1.x, q10);
                    q01 = fdot2p(wF[64 + 4 * C.v + 1], H0.y, q01);
                    q11 = fdot2p(wF[64 + 4 * C.v + 1], H1.y, q11);
                    q00 = fdot2p(wF[64 + 4 * C.v + 2], H0.z, q00);
                    q10 = fdot2p(wF[64 + 4 * C.v + 2], H1.z, q10);
                    q01 = fdot2p(wF[64 + 4 * C.v + 3], H0.w, q01);
                    q11 = fdot2p(wF[64 + 4 * C.v + 3], H1.w, q11);
                });
            }
            for (int i = tid; i < 1024; i += 512) {   // s[tt]: 8 threads per (bb,tt)
                int bb = i >> 9, r = i & 511, tt = r >> 3, pp = r & 7;
                float acc = 0.f;
                #pragma unroll
                for (int c = 0; c < 4; ++c) {
                    float4 wx = *(const float4*)&big[bb][tt * SWF + pp * 16 + c * 4];
                    float4 e4 = *(const float4*)&ebuf[bb][pp * 16 + c * 4];
                    float4 v4 = *(const float4*)&vwf[pp * 16 + c * 4];
                    acc += ftanh(wx.x + e4.x) * v4.x + ftanh(wx.y + e4.y) * v4.y
                         + ftanh(wx.z + e4.z) * v4.z + ftanh(wx.w + e4.w) * v4.w;
                }
                acc += __shfl_xor(acc, 1, 8);
                acc += __shfl_xor(acc, 2, 8);
                acc += __shfl_xor(acc, 4, 8);
                if (pp == 0) sc[bb][tt] = acc + V_b[0];
            }
            __syncthreads();
            if (tid < 128) {   // softmax(64) over time
                int bb = tid >> 6, l = tid & 63;
                float v = sc[bb][l];
                float m = v;
                for (int d = 32; d; d >>= 1) m = fmaxf(m, __shfl_xor(m, d, 64));
                float e = __expf(v - m);
                float s = e;
                for (int d = 32; d; d >>= 1) s += __shfl_xor(s, d, 64);
                att[bb][l] = e / s;
            }
            __syncthreads();
            for (int i = tid; i < 1024; i += 512) {   // din[k], pack pairs 0..63
                int bb = i >> 9, r = i & 511, k = r >> 2, pq = r & 3;
                int kp = k >> 1, kh = k & 1;
                float acc = 0.f;
                #pragma unroll
                for (int u = 0; u < 16; ++u) {
                    int tt = u * 4 + pq;
                    acc += att[bb][tt] * hget(buf_h[bb][tt][kp], kh);
                }
                acc += __shfl_xor(acc, 1, 64);
                acc += __shfl_xor(acc, 2, 64);
                float dp = __shfl_xor(acc, 4, 64);
                if ((r & 7) == 0) xhp[bb][r >> 3] = pkh_d(acc, dp);
            }
            __syncthreads();
            {   // block2: gates_x (pairs 0..63) + combine
                const uint4* x0q = (const uint4*)xhp[0];
                const uint4* x1q = (const uint4*)xhp[1];
                float p00 = bgd, p01 = 0.f, p10 = bgd, p11 = 0.f;
                sfor<16>([&](auto C) {
                    uint4 X0 = x0q[C.v], X1 = x1q[C.v];
                    p00 = fdot2p(wF[4 * C.v + 0], X0.x, p00);
                    p10 = fdot2p(wF[4 * C.v + 0], X1.x, p10);
                    p01 = fdot2p(wF[4 * C.v + 1], X0.y, p01);
                    p11 = fdot2p(wF[4 * C.v + 1], X1.y, p11);
                    p00 = fdot2p(wF[4 * C.v + 2], X0.z, p00);
                    p10 = fdot2p(wF[4 * C.v + 2], X1.z, p10);
                    p01 = fdot2p(wF[4 * C.v + 3], X0.w, p01);
                    p11 = fdot2p(wF[4 * C.v + 3], X1.w, p11);
                });
                pre[0][tid] = (p00 + p01) + (q00 + q01);
                pre[1][tid] = (p10 + p11) + (q10 + q11);
            }
            __syncthreads();
            if (tid < 256) {   // pointwise + fused output partial
                int bb = tid >> 7, k = tid & 127;
                float gi = pre[bb][k], gf = pre[bb][128 + k], gg = pre[bb][256 + k], go = pre[bb][384 + k];
                float c2 = fsig(gf) * creg + fsig(gi) * ftanh(gg);
                float h2v = fsig(go) * ftanh(c2);
                creg = c2;
                float hp = __shfl_xor(h2v, 1, 64);
                float cp = __shfl_xor(c2, 1, 64);
                if (!(k & 1)) {
                    unsigned hu = pkh_d(h2v, hp);
                    hcp[bb][k >> 1] = hu;
                    hcp[bb][64 + (k >> 1)] = pkh_d(c2, cp);
                }
                if (n >= 6) {
                    float v = h2v * rw[k];
                    for (int d = 32; d; d >>= 1) v += __shfl_xor(v, d, 64);
                    if ((tid & 63) == 0) rsm[tid >> 6] = v;
                }
            }
            __syncthreads();
            if (n >= 6 && tid < 2)
                out[(b0 + tid) * TDEC + (n - 6)] = rsm[tid * 2] + rsm[tid * 2 + 1] + reg_b[0];
        }
    }
}

extern "C" void kernel_launch(void* const* d_in, const int* in_sizes, int n_in,
                              void* d_out, int out_size, void* d_ws, size_t ws_size,
                              hipStream_t stream)
{
    const float* inq   = (const float*)d_in[0];
    const float* labp  = (const float*)d_in[1];
    const float* Wih1  = (const float*)d_in[2];
    const float* Whh1  = (const float*)d_in[3];
    const float* bih1  = (const float*)d_in[4];
    const float* bhh1  = (const float*)d_in[5];
    const float* Wih2  = (const float*)d_in[6];
    const float* Whh2  = (const float*)d_in[7];
    const float* bih2  = (const float*)d_in[8];
    const float* bhh2  = (const float*)d_in[9];
    const float* Wihd  = (const float*)d_in[10];
    const float* Whhd  = (const float*)d_in[11];
    const float* bihd  = (const float*)d_in[12];
    const float* bhhd  = (const float*)d_in[13];
    const float* Wi_w  = (const float*)d_in[14];
    const float* Wi_b  = (const float*)d_in[15];
    const float* We_w  = (const float*)d_in[16];
    const float* Vd_w  = (const float*)d_in[17];
    const float* Vd_b  = (const float*)d_in[18];
    const float* Wi2_w = (const float*)d_in[19];
    const float* Wi2_b = (const float*)d_in[20];
    const float* We2_w = (const float*)d_in[21];
    const float* Vd2_w = (const float*)d_in[22];
    const float* Vd2_b = (const float*)d_in[23];
    const float* Wx_w  = (const float*)d_in[24];
    const float* Wx_b  = (const float*)d_in[25];
    const float* Wh_w  = (const float*)d_in[26];
    const float* V_w   = (const float*)d_in[27];
    const float* V_b   = (const float*)d_in[28];
    const float* reg_w = (const float*)d_in[29];
    const float* reg_b = (const float*)d_in[30];
    float* ws  = (float*)d_ws;
    unsigned* wsu = (unsigned*)d_ws;
    float* out = (float*)d_out;

    pack_f2<<<dim3(16, 2), 256, 0, stream>>>(Wi_w, Wi2_w, ws);
    pack_gp<<<73, 512, 0, stream>>>(Wih1, Whh1, 17, 18, 0, U_GB, 512, wsu);
    pack_gp<<<65, 512, 0, stream>>>(Wih2, Whh2, 129, 130, 0, U_GDX, 512, wsu);
    pack_gp<<<64, 512, 0, stream>>>(Wih2, Whh2, 129, 130, 65, U_GDH, 512, wsu);
    pack_gp<<<64, 512, 0, stream>>>(Wihd, Whhd, 128, 128, 0, U_GFX, 512, wsu);
    pack_gp<<<64, 512, 0, stream>>>(Wihd, Whhd, 128, 128, 64, U_GFH, 512, wsu);
    pack_gp<<<64, 128, 0, stream>>>(Wx_w, Wx_w, 128, 128, 0, U_WXH, 128, wsu);
    pack_ew<<<8, 1024, 0, stream>>>(We_w, 64, 8, 16, U_WE, wsu);
    pack_ew<<<8, 1024, 0, stream>>>(We2_w, 64, 8, 16, U_WE2, wsu);
    pack_ew<<<16, 1024, 0, stream>>>(Wh_w, 128, 4, 32, U_WH, wsu);
    dstp_main<<<256, 512, 0, stream>>>(inq, labp, bih1, bhh1, bih2, bhh2, bihd, bhhd,
                                       Wi_b, Vd_w, Vd_b, Wi2_b, Vd2_w, Vd2_b,
                                       Wx_b, V_w, V_b, reg_w, reg_b, ws, out);
}

// Round 13
// 820.158 us; speedup vs baseline: 2.7573x; 2.7573x over previous
//
#include <hip/hip_runtime.h>
#include <hip/hip_fp16.h>

#define TENC 64
#define TDEC 18
#define NDEC 24
#define NF1  17
#define NF2  129
#define HH   128

// ---- ws layout ----
#define OFF_WI   0        // [16][64] float4
#define OFF_WI2  4096     // [16][64] float4
#define U_GB   8192      // [73][512]  phase B gate pairs (x 0..8 | h 9..72)
#define U_GDH  45568     // [64][512]  phase D h-part (pairs 65..128)
#define U_GDX  78336     // [65][512]  phase D x-part (pairs 0..64)
#define U_GFH  111616    // [64][512]  phase F h-part (pairs 64..127)
#define U_GFX  144384    // [64][512]  phase F din-part (pairs 0..63)
#define U_WE   177152    // [64][128]  We   (pr = i*8+pq)
#define U_WE2  185344    // [64][128]  We2
#define U_WH   193536    // [128][128] Wh   (pr = i*4+pq)
#define U_WXH  209920    // [64][128]  Wx f16 pairs

#define SB   68
#define SWF  132
#define XIN  1200
#define BIGN 8772

typedef _Float16 h2t __attribute__((ext_vector_type(2)));

#if defined(__has_builtin)
#if __has_builtin(__builtin_amdgcn_fdot2)
#define HAVE_FDOT2 1
#endif
#endif

template<int I> struct ic_t { static constexpr int v = I; };
template<int N, typename F>
__device__ __forceinline__ void sfor(F&& f)
{
    if constexpr (N > 0) { sfor<N - 1>((F&&)f); f(ic_t<N - 1>{}); }
}

__device__ __forceinline__ float fdot2p(unsigned w, unsigned x, float acc)
{
    h2t hw = __builtin_bit_cast(h2t, w);
    h2t hx = __builtin_bit_cast(h2t, x);
#ifdef HAVE_FDOT2
    return __builtin_amdgcn_fdot2(hw, hx, acc, false);
#else
    return acc + (float)hw.x * (float)hx.x + (float)hw.y * (float)hx.y;
#endif
}

__device__ __forceinline__ unsigned pkh_d(float a, float b)
{
    __half ha = __float2half(a), hb = __float2half(b);
    return (unsigned)__half_as_ushort(ha) | ((unsigned)__half_as_ushort(hb) << 16);
}

__device__ __forceinline__ float hget(unsigned u, int hi)
{
    h2t v = __builtin_bit_cast(h2t, u);
    return hi ? (float)v.y : (float)v.x;
}

__device__ __forceinline__ float fsig(float x) { return 1.f / (1.f + __expf(-x)); }
__device__ __forceinline__ float ftanh(float x)
{
    x = fminf(fmaxf(x, -15.f), 15.f);
    float e = __expf(2.f * x);
    return (e - 1.f) / (e + 1.f);
}

// ---------------- pack kernels ----------------
__global__ void pack_f2(const float* Wi, const float* Wi2, float* ws)
{
    const int m = blockIdx.y;
    const float* src = m ? Wi2 : Wi;
    const int off = m ? OFF_WI2 : OFF_WI;
    const int G = 64, K = 64, n = G * K;
    for (int i = blockIdx.x * blockDim.x + threadIdx.x; i < n; i += gridDim.x * blockDim.x) {
        int q = i & 3, gk = i >> 2;
        int kk = gk / G, g = gk - kk * G;
        ws[off + i] = src[g * K + kk * 4 + q];
    }
}

// pair (qbase+blockIdx.x) of column g = [Wih row g padded to KXP | Whh row g]
__global__ void pack_gp(const float* Wih, const float* Whh, int Kx, int KXP, int qbase,
                        unsigned base, int ldg, unsigned* wsu)
{
    const int g = threadIdx.x;
    const int q = qbase + blockIdx.x;
    int k0 = 2 * q, k1 = 2 * q + 1;
    float f0 = (k0 < KXP) ? ((k0 < Kx) ? Wih[g * Kx + k0] : 0.f) : Whh[g * HH + (k0 - KXP)];
    float f1 = (k1 < KXP) ? ((k1 < Kx) ? Wih[g * Kx + k1] : 0.f) : Whh[g * HH + (k1 - KXP)];
    wsu[base + (unsigned)blockIdx.x * (unsigned)ldg + g] = pkh_d(f0, f1);
}

// e-weights: dst[j*128 + pq*nI + i] = pair (i*nPQ + pq) of row j
__global__ void pack_ew(const float* W, int J, int nPQ, int nI, unsigned base, unsigned* wsu)
{
    int idx = blockIdx.x * blockDim.x + threadIdx.x;
    if (idx >= J * 128) return;
    int j = idx >> 7, r = idx & 127;
    int pq = r / nI, i = r - pq * nI;
    int pr = i * nPQ + pq;
    wsu[base + idx] = pkh_d(W[j * 256 + 2 * pr], W[j * 256 + 2 * pr + 1]);
}

// ---------------- main kernel: 512 threads, 2 batch elems/WG, grid 256 ----------------
// 1 WG/CU (LDS 114KB => 2 waves/SIMD => 256 VGPR budget). All phase weights
// register-resident; gate x-broadcasts via wave-uniform ds_read_b128 (LDS pipe)
// instead of v_readlane (VALU pipe); 4 accumulator chains per elem.
// NOTE (R12 lesson): no values may live across __syncthreads in the step loop
// beyond creg — cross-barrier partials trigger scratch demotion of the weight
// arrays (FETCH blows up to GBs while VGPR_Count still reads 128).
__global__ __launch_bounds__(512, 2)
void dstp_main(const float* __restrict__ inq, const float* __restrict__ labp,
               const float* __restrict__ bih1, const float* __restrict__ bhh1,
               const float* __restrict__ bih2, const float* __restrict__ bhh2,
               const float* __restrict__ bihd, const float* __restrict__ bhhd,
               const float* __restrict__ Wi_b, const float* __restrict__ Vd_w, const float* __restrict__ Vd_b,
               const float* __restrict__ Wi2_b, const float* __restrict__ Vd2_w, const float* __restrict__ Vd2_b,
               const float* __restrict__ Wx_b, const float* __restrict__ V_w, const float* __restrict__ V_b,
               const float* __restrict__ reg_w, const float* __restrict__ reg_b,
               const float* __restrict__ ws, float* __restrict__ out)
{
    __shared__ __align__(16) unsigned buf_h[2][TENC][64];   // mid/final h as f16 pairs
    __shared__ __align__(16) float big[2][BIGN];            // WiX+xin / Wi2X / WxF
    __shared__ __align__(16) unsigned hcp[2][128];          // f16 pairs: h 0..63 | c 64..127
    __shared__ __align__(16) unsigned xhp[2][132];          // broadcast pairs (linear gate order)
    __shared__ __align__(16) float ebuf[2][128];
    __shared__ float sc[2][132];
    __shared__ float att[2][64];
    __shared__ float pre[2][512];
    __shared__ float lab[2][64];
    __shared__ __align__(16) float vw1[64], vw2[64], vwf[128], rw[128];
    __shared__ float rsm[4];

    const int tid  = threadIdx.x;
    const int b0   = blockIdx.x * 2;
    const unsigned* wsu = (const unsigned*)ws;
    const float4* Wip  = (const float4*)(ws + OFF_WI);
    const float4* Wi2p = (const float4*)(ws + OFF_WI2);

    const float bg1 = bih1[tid] + bhh1[tid];
    const float bg2 = bih2[tid] + bhh2[tid];
    const float bgd = bihd[tid] + bhhd[tid];
    float creg = 0.f;   // fp32 cell state (pointwise thread tid<256, per bb)

    // ================= Phase A: inputs, WiX =================
    if (tid < 128) lab[tid >> 6][tid & 63] = labp[(b0 + (tid >> 6)) * TENC + (tid & 63)];
    if (tid < 64)        vw1[tid]       = Vd_w[tid];
    else if (tid < 128)  vw2[tid - 64]  = Vd2_w[tid - 64];
    else if (tid < 256)  vwf[tid - 128] = V_w[tid - 128];
    else if (tid < 384)  rw[tid - 256]  = reg_w[tid - 256];
    for (int i = tid; i < 2176; i += 512) {           // xin: x[t][f], COLS skip 14
        int bb = i / 1088, r = i - bb * 1088, t = r / NF1, f = r - t * NF1;
        big[bb][XIN + r] = inq[((b0 + bb) * TENC + t) * 18 + f + (f >= 14)];
    }
    __syncthreads();
    for (int i = tid; i < 2176; i += 512) {           // WiX[f][j]
        int bb = i / 1088, r = i - bb * 1088, f = r >> 6, j = r & 63;
        float acc = Wi_b[j];
        for (int tt = 0; tt < 16; ++tt) {
            float4 w = Wip[tt * 64 + j];
            acc += big[bb][XIN + (4 * tt + 0) * NF1 + f] * w.x
                 + big[bb][XIN + (4 * tt + 1) * NF1 + f] * w.y
                 + big[bb][XIN + (4 * tt + 2) * NF1 + f] * w.z
                 + big[bb][XIN + (4 * tt + 3) * NF1 + f] * w.w;
        }
        big[bb][f * SB + j] = acc;
    }

    // ================= Phase B: encoder scan 1 (fully resident) =================
    {
        if (tid < 256) hcp[tid >> 7][tid & 127] = 0u;
        if (tid < 264) xhp[tid / 132][tid % 132] = 0u;
        creg = 0.f;
        unsigned wB[73];
        sfor<73>([&](auto I) { wB[I.v] = wsu[U_GB + I.v * 512 + tid]; });
        unsigned we[16];
        const int ewb = U_WE + ((tid >> 3) << 7) + ((tid & 7) << 4);
        sfor<16>([&](auto I) { we[I.v] = wsu[ewb + I.v]; });
        __syncthreads();

        for (int t = 0; t < TENC; ++t) {
            {   // e[j] for both elems, 2 chains/elem
                int j = tid >> 3, pq = tid & 7;
                float a0 = 0.f, a1 = 0.f, b0c = 0.f, b1c = 0.f;
                sfor<8>([&](auto I) {
                    a0  = fdot2p(we[I.v], hcp[0][I.v * 8 + pq], a0);
                    a1  = fdot2p(we[I.v], hcp[1][I.v * 8 + pq], a1);
                    b0c = fdot2p(we[8 + I.v], hcp[0][(8 + I.v) * 8 + pq], b0c);
                    b1c = fdot2p(we[8 + I.v], hcp[1][(8 + I.v) * 8 + pq], b1c);
                });
                float s0 = a0 + b0c, s1 = a1 + b1c;
                s0 += __shfl_xor(s0, 1, 8); s1 += __shfl_xor(s1, 1, 8);
                s0 += __shfl_xor(s0, 2, 8); s1 += __shfl_xor(s1, 2, 8);
                s0 += __shfl_xor(s0, 4, 8); s1 += __shfl_xor(s1, 4, 8);
                if (pq == 0) { ebuf[0][j] = s0; ebuf[1][j] = s1; }
            }
            __syncthreads();
            for (int i = tid; i < 544; i += 512) {   // score[f]: 16 threads per (bb,f)
                int bb = i / 272, r = i - bb * 272, f = r >> 4, pp = r & 15;
                float4 wx = *(const float4*)&big[bb][f * SB + pp * 4];
                float4 e4 = *(const float4*)&ebuf[bb][pp * 4];
                float4 v4 = *(const float4*)&vw1[pp * 4];
                float acc = ftanh(wx.x + e4.x) * v4.x + ftanh(wx.y + e4.y) * v4.y
                          + ftanh(wx.z + e4.z) * v4.z + ftanh(wx.w + e4.w) * v4.w;
                acc += __shfl_xor(acc, 1, 16);
                acc += __shfl_xor(acc, 2, 16);
                acc += __shfl_xor(acc, 4, 16);
                acc += __shfl_xor(acc, 8, 16);
                if (pp == 0) sc[bb][f] = acc + Vd_b[0];
            }
            __syncthreads();
            if (tid < 128) {   // softmax(17) + pack x pairs 0..8
                int bb = tid >> 6, l = tid & 63;
                float v = (l < NF1) ? sc[bb][l] : -1e30f;
                float m = v;
                for (int d = 32; d; d >>= 1) m = fmaxf(m, __shfl_xor(m, d, 64));
                float e = (l < NF1) ? __expf(v - m) : 0.f;
                float s = e;
                for (int d = 32; d; d >>= 1) s += __shfl_xor(s, d, 64);
                float xv = (l < NF1) ? big[bb][XIN + t * NF1 + l] * (e / s) : 0.f;
                float xp = __shfl_xor(xv, 1, 64);
                if (!(l & 1) && l < 18) xhp[bb][l >> 1] = pkh_d(xv, xp);
            }
            __syncthreads();
            {   // gates: pairs 0..72 linear; uniform b128 broadcasts, 4 chains/elem
                const uint4* x0q = (const uint4*)xhp[0];
                const uint4* x1q = (const uint4*)xhp[1];
                float p00 = bg1, p01 = 0.f, p02 = 0.f, p03 = 0.f;
                float p10 = bg1, p11 = 0.f, p12 = 0.f, p13 = 0.f;
                sfor<18>([&](auto C) {
                    uint4 X0 = x0q[C.v], X1 = x1q[C.v];
                    p00 = fdot2p(wB[4 * C.v + 0], X0.x, p00);
                    p10 = fdot2p(wB[4 * C.v + 0], X1.x, p10);
                    p01 = fdot2p(wB[4 * C.v + 1], X0.y, p01);
                    p11 = fdot2p(wB[4 * C.v + 1], X1.y, p11);
                    p02 = fdot2p(wB[4 * C.v + 2], X0.z, p02);
                    p12 = fdot2p(wB[4 * C.v + 2], X1.z, p12);
                    p03 = fdot2p(wB[4 * C.v + 3], X0.w, p03);
                    p13 = fdot2p(wB[4 * C.v + 3], X1.w, p13);
                });
                p00 = fdot2p(wB[72], xhp[0][72], p00);
                p10 = fdot2p(wB[72], xhp[1][72], p10);
                pre[0][tid] = (p00 + p01) + (p02 + p03);
                pre[1][tid] = (p10 + p11) + (p12 + p13);
            }
            __syncthreads();
            if (tid < 256) {   // LSTM pointwise
                int bb = tid >> 7, k = tid & 127;
                float gi = pre[bb][k], gf = pre[bb][128 + k], gg = pre[bb][256 + k], go = pre[bb][384 + k];
                float c2 = fsig(gf) * creg + fsig(gi) * ftanh(gg);
                float h2v = fsig(go) * ftanh(c2);
                creg = c2;
                float hp = __shfl_xor(h2v, 1, 64);
                float cp = __shfl_xor(c2, 1, 64);
                if (!(k & 1)) {
                    unsigned hu = pkh_d(h2v, hp);
                    hcp[bb][k >> 1] = hu;
                    hcp[bb][64 + (k >> 1)] = pkh_d(c2, cp);
                    xhp[bb][9 + (k >> 1)] = hu;
                    buf_h[bb][t][k >> 1] = hu;    // mid as f16 pair
                }
            }
            __syncthreads();
        }
    }

    // ================= Phase C: Wi2X (reads f16 mid) =================
    if (tid < 256) hcp[tid >> 7][tid & 127] = 0u;
    if (tid < 264) xhp[tid / 132][tid % 132] = 0u;
    creg = 0.f;
    for (int i = tid; i < 16512; i += 512) {
        int bb = i / 8256, r = i - bb * 8256, f = r >> 6, j = r & 63;
        float acc = Wi2_b[j];
        if (f < HH) {
            int fp = f >> 1, fh = f & 1;
            for (int tt = 0; tt < 16; ++tt) {
                float4 w = Wi2p[tt * 64 + j];
                acc += hget(buf_h[bb][4 * tt + 0][fp], fh) * w.x
                     + hget(buf_h[bb][4 * tt + 1][fp], fh) * w.y
                     + hget(buf_h[bb][4 * tt + 2][fp], fh) * w.z
                     + hget(buf_h[bb][4 * tt + 3][fp], fh) * w.w;
            }
        } else {
            for (int tt = 0; tt < 16; ++tt) {
                float4 w = Wi2p[tt * 64 + j];
                acc += lab[bb][4 * tt] * w.x + lab[bb][4 * tt + 1] * w.y
                     + lab[bb][4 * tt + 2] * w.z + lab[bb][4 * tt + 3] * w.w;
            }
        }
        big[bb][f * SB + j] = acc;
    }

    // ================= Phase D: encoder scan 2 (fully resident) =================
    {
        unsigned wD[129];   // pairs 0..64 = x part, 65..128 = h part (linear xhp order)
        sfor<65>([&](auto I) { wD[I.v] = wsu[U_GDX + I.v * 512 + tid]; });
        sfor<64>([&](auto I) { wD[65 + I.v] = wsu[U_GDH + I.v * 512 + tid]; });
        unsigned wes[16];
        const int ewb2 = U_WE2 + ((tid >> 3) << 7) + ((tid & 7) << 4);
        sfor<16>([&](auto I) { wes[I.v] = wsu[ewb2 + I.v]; });
        __syncthreads();

        for (int t = 0; t < TENC; ++t) {
            {   // e[j] both elems, 2 chains/elem
                int j = tid >> 3, pq = tid & 7;
                float a0 = 0.f, a1 = 0.f, b0c = 0.f, b1c = 0.f;
                sfor<8>([&](auto I) {
                    a0  = fdot2p(wes[I.v], hcp[0][I.v * 8 + pq], a0);
                    a1  = fdot2p(wes[I.v], hcp[1][I.v * 8 + pq], a1);
                    b0c = fdot2p(wes[8 + I.v], hcp[0][(8 + I.v) * 8 + pq], b0c);
                    b1c = fdot2p(wes[8 + I.v], hcp[1][(8 + I.v) * 8 + pq], b1c);
                });
                float s0 = a0 + b0c, s1 = a1 + b1c;
                s0 += __shfl_xor(s0, 1, 8); s1 += __shfl_xor(s1, 1, 8);
                s0 += __shfl_xor(s0, 2, 8); s1 += __shfl_xor(s1, 2, 8);
                s0 += __shfl_xor(s0, 4, 8); s1 += __shfl_xor(s1, 4, 8);
                if (pq == 0) { ebuf[0][j] = s0; ebuf[1][j] = s1; }
            }
            __syncthreads();
            for (int i = tid; i < 1032; i += 512) {   // score[f]: 4 threads per (bb,f)
                int bb = i / 516, r = i - bb * 516, f = r >> 2, pp = r & 3;
                float acc = 0.f;
                #pragma unroll
                for (int c = 0; c < 4; ++c) {
                    float4 wx = *(const float4*)&big[bb][f * SB + pp * 16 + c * 4];
                    float4 e4 = *(const float4*)&ebuf[bb][pp * 16 + c * 4];
                    float4 v4 = *(const float4*)&vw2[pp * 16 + c * 4];
                    acc += ftanh(wx.x + e4.x) * v4.x + ftanh(wx.y + e4.y) * v4.y
                         + ftanh(wx.z + e4.z) * v4.z + ftanh(wx.w + e4.w) * v4.w;
                }
                acc += __shfl_xor(acc, 1, 4);
                acc += __shfl_xor(acc, 2, 4);
                if (pp == 0) sc[bb][f] = acc + Vd2_b[0];
            }
            __syncthreads();
            if (tid < 128) {   // softmax(129) + pack x pairs 0..64
                int bb = tid >> 6, l = tid & 63;
                float s1 = sc[bb][l], s2 = sc[bb][l + 64];
                float s3 = (l == 0) ? sc[bb][128] : -1e30f;
                float m = fmaxf(fmaxf(s1, s2), s3);
                for (int d = 32; d; d >>= 1) m = fmaxf(m, __shfl_xor(m, d, 64));
                float e1 = __expf(s1 - m), e2 = __expf(s2 - m);
                float e3 = (l == 0) ? __expf(s3 - m) : 0.f;
                float s = e1 + e2 + e3;
                for (int d = 32; d; d >>= 1) s += __shfl_xor(s, d, 64);
                float inv = 1.f / s;
                float v1 = hget(buf_h[bb][t][l >> 1], l & 1) * e1 * inv;
                float v2 = hget(buf_h[bb][t][32 + (l >> 1)], l & 1) * e2 * inv;
                float v1p = __shfl_xor(v1, 1, 64);
                float v2p = __shfl_xor(v2, 1, 64);
                if (!(l & 1)) {
                    xhp[bb][l >> 1] = pkh_d(v1, v1p);
                    xhp[bb][32 + (l >> 1)] = pkh_d(v2, v2p);
                }
                if (l == 0) xhp[bb][64] = pkh_d(lab[bb][t] * e3 * inv, 0.f);
            }
            __syncthreads();
            {   // gates: pairs 0..128 linear; uniform b128 broadcasts, 4 chains/elem
                const uint4* x0q = (const uint4*)xhp[0];
                const uint4* x1q = (const uint4*)xhp[1];
                float p00 = bg2, p01 = 0.f, p02 = 0.f, p03 = 0.f;
                float p10 = bg2, p11 = 0.f, p12 = 0.f, p13 = 0.f;
                sfor<32>([&](auto C) {
                    uint4 X0 = x0q[C.v], X1 = x1q[C.v];
                    p00 = fdot2p(wD[4 * C.v + 0], X0.x, p00);
                    p10 = fdot2p(wD[4 * C.v + 0], X1.x, p10);
                    p01 = fdot2p(wD[4 * C.v + 1], X0.y, p01);
                    p11 = fdot2p(wD[4 * C.v + 1], X1.y, p11);
                    p02 = fdot2p(wD[4 * C.v + 2], X0.z, p02);
                    p12 = fdot2p(wD[4 * C.v + 2], X1.z, p12);
                    p03 = fdot2p(wD[4 * C.v + 3], X0.w, p03);
                    p13 = fdot2p(wD[4 * C.v + 3], X1.w, p13);
                });
                p00 = fdot2p(wD[128], xhp[0][128], p00);
                p10 = fdot2p(wD[128], xhp[1][128], p10);
                pre[0][tid] = (p00 + p01) + (p02 + p03);
                pre[1][tid] = (p10 + p11) + (p12 + p13);
            }
            __syncthreads();
            if (tid < 256) {
                int bb = tid >> 7, k = tid & 127;
                float gi = pre[bb][k], gf = pre[bb][128 + k], gg = pre[bb][256 + k], go = pre[bb][384 + k];
                float c2 = fsig(gf) * creg + fsig(gi) * ftanh(gg);
                float h2v = fsig(go) * ftanh(c2);
                creg = c2;
                float hp = __shfl_xor(h2v, 1, 64);
                float cp = __shfl_xor(c2, 1, 64);
                if (!(k & 1)) {
                    unsigned hu = pkh_d(h2v, hp);
                    hcp[bb][k >> 1] = hu;
                    hcp[bb][64 + (k >> 1)] = pkh_d(c2, cp);
                    xhp[bb][65 + (k >> 1)] = hu;
                    buf_h[bb][t][k >> 1] = hu;    // final overwrites consumed mid row
                }
            }
            __syncthreads();
        }
    }

    // ================= Phase E: WxF via f16 fdot2 (b128 broadcast reads) =================
    if (tid < 256) hcp[tid >> 7][tid & 127] = 0u;
    if (tid < 264) xhp[tid / 132][tid % 132] = 0u;
    creg = 0.f;
    {
        const int j = tid & 127;
        unsigned wxh[64];
        sfor<64>([&](auto I) { wxh[I.v] = wsu[U_WXH + I.v * 128 + j]; });
        for (int u = tid >> 7; u < 128; u += 4) {
            int bb = u >> 6, tt = u & 63;
            const uint4* bq = (const uint4*)buf_h[bb][tt];
            float a0 = Wx_b[j], a1 = 0.f, a2 = 0.f, a3 = 0.f;
            sfor<16>([&](auto C) {
                uint4 X = bq[C.v];
                a0 = fdot2p(wxh[4 * C.v + 0], X.x, a0);
                a1 = fdot2p(wxh[4 * C.v + 1], X.y, a1);
                a2 = fdot2p(wxh[4 * C.v + 2], X.z, a2);
                a3 = fdot2p(wxh[4 * C.v + 3], X.w, a3);
            });
            big[bb][tt * SWF + j] = (a0 + a1) + (a2 + a3);
        }
    }

    // ================= Phase F: decoder (fully resident) =================
    {
        unsigned wF[128];   // pairs 0..63 = din part, 64..127 = h part (linear xhp order)
        sfor<64>([&](auto I) { wF[I.v] = wsu[U_GFX + I.v * 512 + tid]; });
        sfor<64>([&](auto I) { wF[64 + I.v] = wsu[U_GFH + I.v * 512 + tid]; });
        unsigned wh[32];
        const int whb = U_WH + ((tid >> 2) << 7) + ((tid & 3) << 5);
        sfor<32>([&](auto I) { wh[I.v] = wsu[whb + I.v]; });
        __syncthreads();

        for (int n = 0; n < NDEC; ++n) {
            {   // e[j] both elems, 2 chains/elem
                int j = tid >> 2, pq = tid & 3;
                float a0 = 0.f, a1 = 0.f, b0c = 0.f, b1c = 0.f;
                sfor<16>([&](auto I) {
                    a0  = fdot2p(wh[I.v], hcp[0][I.v * 4 + pq], a0);
                    a1  = fdot2p(wh[I.v], hcp[1][I.v * 4 + pq], a1);
                    b0c = fdot2p(wh[16 + I.v], hcp[0][(16 + I.v) * 4 + pq], b0c);
                    b1c = fdot2p(wh[16 + I.v], hcp[1][(16 + I.v) * 4 + pq], b1c);
                });
                float s0 = a0 + b0c, s1 = a1 + b1c;
                s0 += __shfl_xor(s0, 1, 4); s1 += __shfl_xor(s1, 1, 4);
                s0 += __shfl_xor(s0, 2, 4); s1 += __shfl_xor(s1, 2, 4);
                if (pq == 0) { ebuf[0][j] = s0; ebuf[1][j] = s1; }
            }
            __syncthreads();
            for (int i = tid; i < 1024; i += 512) {   // s[tt]: 8 threads per (bb,tt)
                int bb = i >> 9, r = i & 511, tt = r >> 3, pp = r & 7;
                float acc = 0.f;
                #pragma unroll
                for (int c = 0; c < 4; ++c) {
                    float4 wx = *(const float4*)&big[bb][tt * SWF + pp * 16 + c * 4];
                    float4 e4 = *(const float4*)&ebuf[bb][pp * 16 + c * 4];
                    float4 v4 = *(const float4*)&vwf[pp * 16 + c * 4];
                    acc += ftanh(wx.x + e4.x) * v4.x + ftanh(wx.y + e4.y) * v4.y
                         + ftanh(wx.z + e4.z) * v4.z + ftanh(wx.w + e4.w) * v4.w;
                }
                acc += __shfl_xor(acc, 1, 8);
                acc += __shfl_xor(acc, 2, 8);
                acc += __shfl_xor(acc, 4, 8);
                if (pp == 0) sc[bb][tt] = acc + V_b[0];
            }
            __syncthreads();
            if (tid < 128) {   // softmax(64) over time
                int bb = tid >> 6, l = tid & 63;
                float v = sc[bb][l];
                float m = v;
                for (int d = 32; d; d >>= 1) m = fmaxf(m, __shfl_xor(m, d, 64));
                float e = __expf(v - m);
                float s = e;
                for (int d = 32; d; d >>= 1) s += __shfl_xor(s, d, 64);
                att[bb][l] = e / s;
            }
            __syncthreads();
            for (int i = tid; i < 1024; i += 512) {   // din[k], pack pairs 0..63
                int bb = i >> 9, r = i & 511, k = r >> 2, pq = r & 3;
                int kp = k >> 1, kh = k & 1;
                float acc = 0.f;
                #pragma unroll
                for (int u = 0; u < 16; ++u) {
                    int tt = u * 4 + pq;
                    acc += att[bb][tt] * hget(buf_h[bb][tt][kp], kh);
                }
                acc += __shfl_xor(acc, 1, 64);
                acc += __shfl_xor(acc, 2, 64);
                float dp = __shfl_xor(acc, 4, 64);
                if ((r & 7) == 0) xhp[bb][r >> 3] = pkh_d(acc, dp);
            }
            __syncthreads();
            {   // gates: pairs 0..127 linear; uniform b128 broadcasts, 4 chains/elem
                const uint4* x0q = (const uint4*)xhp[0];
                const uint4* x1q = (const uint4*)xhp[1];
                float p00 = bgd, p01 = 0.f, p02 = 0.f, p03 = 0.f;
                float p10 = bgd, p11 = 0.f, p12 = 0.f, p13 = 0.f;
                sfor<32>([&](auto C) {
                    uint4 X0 = x0q[C.v], X1 = x1q[C.v];
                    p00 = fdot2p(wF[4 * C.v + 0], X0.x, p00);
                    p10 = fdot2p(wF[4 * C.v + 0], X1.x, p10);
                    p01 = fdot2p(wF[4 * C.v + 1], X0.y, p01);
                    p11 = fdot2p(wF[4 * C.v + 1], X1.y, p11);
                    p02 = fdot2p(wF[4 * C.v + 2], X0.z, p02);
                    p12 = fdot2p(wF[4 * C.v + 2], X1.z, p12);
                    p03 = fdot2p(wF[4 * C.v + 3], X0.w, p03);
                    p13 = fdot2p(wF[4 * C.v + 3], X1.w, p13);
                });
                pre[0][tid] = (p00 + p01) + (p02 + p03);
                pre[1][tid] = (p10 + p11) + (p12 + p13);
            }
            __syncthreads();
            if (tid < 256) {   // pointwise + fused output partial
                int bb = tid >> 7, k = tid & 127;
                float gi = pre[bb][k], gf = pre[bb][128 + k], gg = pre[bb][256 + k], go = pre[bb][384 + k];
                float c2 = fsig(gf) * creg + fsig(gi) * ftanh(gg);
                float h2v = fsig(go) * ftanh(c2);
                creg = c2;
                float hp = __shfl_xor(h2v, 1, 64);
                float cp = __shfl_xor(c2, 1, 64);
                if (!(k & 1)) {
                    unsigned hu = pkh_d(h2v, hp);
                    hcp[bb][k >> 1] = hu;
                    hcp[bb][64 + (k >> 1)] = pkh_d(c2, cp);
                    xhp[bb][64 + (k >> 1)] = hu;
                }
                if (n >= 6) {
                    float v = h2v * rw[k];
                    for (int d = 32; d; d >>= 1) v += __shfl_xor(v, d, 64);
                    if ((tid & 63) == 0) rsm[tid >> 6] = v;
                }
            }
            __syncthreads();
            if (n >= 6 && tid < 2)
                out[(b0 + tid) * TDEC + (n - 6)] = rsm[tid * 2] + rsm[tid * 2 + 1] + reg_b[0];
        }
    }
}

extern "C" void kernel_launch(void* const* d_in, const int* in_sizes, int n_in,
                              void* d_out, int out_size, void* d_ws, size_t ws_size,
                              hipStream_t stream)
{
    const float* inq   = (const float*)d_in[0];
    const float* labp  = (const float*)d_in[1];
    const float* Wih1  = (const float*)d_in[2];
    const float* Whh1  = (const float*)d_in[3];
    const float* bih1  = (const float*)d_in[4];
    const float* bhh1  = (const float*)d_in[5];
    const float* Wih2  = (const float*)d_in[6];
    const float* Whh2  = (const float*)d_in[7];
    const float* bih2  = (const float*)d_in[8];
    const float* bhh2  = (const float*)d_in[9];
    const float* Wihd  = (const float*)d_in[10];
    const float* Whhd  = (const float*)d_in[11];
    const float* bihd  = (const float*)d_in[12];
    const float* bhhd  = (const float*)d_in[13];
    const float* Wi_w  = (const float*)d_in[14];
    const float* Wi_b  = (const float*)d_in[15];
    const float* We_w  = (const float*)d_in[16];
    const float* Vd_w  = (const float*)d_in[17];
    const float* Vd_b  = (const float*)d_in[18];
    const float* Wi2_w = (const float*)d_in[19];
    const float* Wi2_b = (const float*)d_in[20];
    const float* We2_w = (const float*)d_in[21];
    const float* Vd2_w = (const float*)d_in[22];
    const float* Vd2_b = (const float*)d_in[23];
    const float* Wx_w  = (const float*)d_in[24];
    const float* Wx_b  = (const float*)d_in[25];
    const float* Wh_w  = (const float*)d_in[26];
    const float* V_w   = (const float*)d_in[27];
    const float* V_b   = (const float*)d_in[28];
    const float* reg_w = (const float*)d_in[29];
    const float* reg_b = (const float*)d_in[30];
    float* ws  = (float*)d_ws;
    unsigned* wsu = (unsigned*)d_ws;
    float* out = (float*)d_out;

    pack_f2<<<dim3(16, 2), 256, 0, stream>>>(Wi_w, Wi2_w, ws);
    pack_gp<<<73, 512, 0, stream>>>(Wih1, Whh1, 17, 18, 0, U_GB, 512, wsu);
    pack_gp<<<65, 512, 0, stream>>>(Wih2, Whh2, 129, 130, 0, U_GDX, 512, wsu);
    pack_gp<<<64, 512, 0, stream>>>(Wih2, Whh2, 129, 130, 65, U_GDH, 512, wsu);
    pack_gp<<<64, 512, 0, stream>>>(Wihd, Whhd, 128, 128, 0, U_GFX, 512, wsu);
    pack_gp<<<64, 512, 0, stream>>>(Wihd, Whhd, 128, 128, 64, U_GFH, 512, wsu);
    pack_gp<<<64, 128, 0, stream>>>(Wx_w, Wx_w, 128, 128, 0, U_WXH, 128, wsu);
    pack_ew<<<8, 1024, 0, stream>>>(We_w, 64, 8, 16, U_WE, wsu);
    pack_ew<<<8, 1024, 0, stream>>>(We2_w, 64, 8, 16, U_WE2, wsu);
    pack_ew<<<16, 1024, 0, stream>>>(Wh_w, 128, 4, 32, U_WH, wsu);
    dstp_main<<<256, 512, 0, stream>>>(inq, labp, bih1, bhh1, bih2, bhh2, bihd, bhhd,
                                       Wi_b, Vd_w, Vd_b, Wi2_b, Vd2_w, Vd2_b,
                                       Wx_b, V_w, V_b, reg_w, reg_b, ws, out);
}

// Round 14
// 797.032 us; speedup vs baseline: 2.8373x; 1.0290x over previous
//
#include <hip/hip_runtime.h>
#include <hip/hip_fp16.h>

#define TENC 64
#define TDEC 18
#define NDEC 24
#define NF1  17
#define NF2  129
#define HH   128

// ---- ws layout ----
#define OFF_WI   0        // [16][64] float4
#define OFF_WI2  4096     // [16][64] float4
#define U_GB   8192      // [73][512]  phase B gate pairs (x 0..8 | h 9..72)
#define U_GDH  45568     // [64][512]  phase D h-part (pairs 65..128)
#define U_GDX  78336     // [65][512]  phase D x-part (pairs 0..64)
#define U_GFH  111616    // [64][512]  phase F h-part (pairs 64..127)
#define U_GFX  144384    // [64][512]  phase F din-part (pairs 0..63)
#define U_WE   177152    // [64][128]  We   (pr = i*8+pq)
#define U_WE2  185344    // [64][128]  We2
#define U_WH   193536    // [128][128] Wh   (pr = i*4+pq)
#define U_WXH  209920    // [64][128]  Wx f16 pairs

#define SB   68
#define SWF  132
#define XIN  1200
#define BIGN 8772

typedef _Float16 h2t __attribute__((ext_vector_type(2)));

#if defined(__has_builtin)
#if __has_builtin(__builtin_amdgcn_fdot2)
#define HAVE_FDOT2 1
#endif
#endif

template<int I> struct ic_t { static constexpr int v = I; };
template<int N, typename F>
__device__ __forceinline__ void sfor(F&& f)
{
    if constexpr (N > 0) { sfor<N - 1>((F&&)f); f(ic_t<N - 1>{}); }
}

__device__ __forceinline__ float fdot2p(unsigned w, unsigned x, float acc)
{
    h2t hw = __builtin_bit_cast(h2t, w);
    h2t hx = __builtin_bit_cast(h2t, x);
#ifdef HAVE_FDOT2
    return __builtin_amdgcn_fdot2(hw, hx, acc, false);
#else
    return acc + (float)hw.x * (float)hx.x + (float)hw.y * (float)hx.y;
#endif
}

__device__ __forceinline__ unsigned pkh_d(float a, float b)
{
    __half ha = __float2half(a), hb = __float2half(b);
    return (unsigned)__half_as_ushort(ha) | ((unsigned)__half_as_ushort(hb) << 16);
}

__device__ __forceinline__ float hget(unsigned u, int hi)
{
    h2t v = __builtin_bit_cast(h2t, u);
    return hi ? (float)v.y : (float)v.x;
}

__device__ __forceinline__ float fsig(float x) { return 1.f / (1.f + __expf(-x)); }
__device__ __forceinline__ float ftanh(float x)
{
    x = fminf(fmaxf(x, -15.f), 15.f);
    float e = __expf(2.f * x);
    return (e - 1.f) / (e + 1.f);
}

// ---------------- pack kernels ----------------
__global__ void pack_f2(const float* Wi, const float* Wi2, float* ws)
{
    const int m = blockIdx.y;
    const float* src = m ? Wi2 : Wi;
    const int off = m ? OFF_WI2 : OFF_WI;
    const int G = 64, K = 64, n = G * K;
    for (int i = blockIdx.x * blockDim.x + threadIdx.x; i < n; i += gridDim.x * blockDim.x) {
        int q = i & 3, gk = i >> 2;
        int kk = gk / G, g = gk - kk * G;
        ws[off + i] = src[g * K + kk * 4 + q];
    }
}

// pair (qbase+blockIdx.x) of column g = [Wih row g padded to KXP | Whh row g]
__global__ void pack_gp(const float* Wih, const float* Whh, int Kx, int KXP, int qbase,
                        unsigned base, int ldg, unsigned* wsu)
{
    const int g = threadIdx.x;
    const int q = qbase + blockIdx.x;
    int k0 = 2 * q, k1 = 2 * q + 1;
    float f0 = (k0 < KXP) ? ((k0 < Kx) ? Wih[g * Kx + k0] : 0.f) : Whh[g * HH + (k0 - KXP)];
    float f1 = (k1 < KXP) ? ((k1 < Kx) ? Wih[g * Kx + k1] : 0.f) : Whh[g * HH + (k1 - KXP)];
    wsu[base + (unsigned)blockIdx.x * (unsigned)ldg + g] = pkh_d(f0, f1);
}

// e-weights: dst[j*128 + pq*nI + i] = pair (i*nPQ + pq) of row j
__global__ void pack_ew(const float* W, int J, int nPQ, int nI, unsigned base, unsigned* wsu)
{
    int idx = blockIdx.x * blockDim.x + threadIdx.x;
    if (idx >= J * 128) return;
    int j = idx >> 7, r = idx & 127;
    int pq = r / nI, i = r - pq * nI;
    int pr = i * nPQ + pq;
    wsu[base + idx] = pkh_d(W[j * 256 + 2 * pr], W[j * 256 + 2 * pr + 1]);
}

// ---------------- main kernel: 512 threads, 2 batch elems/WG, grid 256 ----------------
// 1 WG/CU. All phase weights register-resident (AGPR overflow OK). gates_h is
// computed in the score block (trans-pipe heavy) and banked to LDS preH — the
// partials DIE before the barrier (R12 lesson: cross-barrier scalars cause
// true scratch spill). Softmax skips the max pass (scores bounded: |s|<=8).
__global__ __launch_bounds__(512, 2)
void dstp_main(const float* __restrict__ inq, const float* __restrict__ labp,
               const float* __restrict__ bih1, const float* __restrict__ bhh1,
               const float* __restrict__ bih2, const float* __restrict__ bhh2,
               const float* __restrict__ bihd, const float* __restrict__ bhhd,
               const float* __restrict__ Wi_b, const float* __restrict__ Vd_w, const float* __restrict__ Vd_b,
               const float* __restrict__ Wi2_b, const float* __restrict__ Vd2_w, const float* __restrict__ Vd2_b,
               const float* __restrict__ Wx_b, const float* __restrict__ V_w, const float* __restrict__ V_b,
               const float* __restrict__ reg_w, const float* __restrict__ reg_b,
               const float* __restrict__ ws, float* __restrict__ out)
{
    __shared__ __align__(16) unsigned buf_h[2][TENC][64];   // mid/final h as f16 pairs
    __shared__ __align__(16) float big[2][BIGN];            // WiX+xin / Wi2X / WxF
    __shared__ __align__(16) unsigned hcp[2][128];          // f16 pairs: h 0..63 | c 64..127
    __shared__ __align__(16) unsigned xhp[2][132];          // broadcast pairs (x/din parts)
    __shared__ __align__(16) float ebuf[2][128];
    __shared__ float sc[2][132];
    __shared__ float att[2][64];
    __shared__ float pre[2][512];
    __shared__ float preH[2][512];                          // gates_h partials handoff
    __shared__ float lab[2][64];
    __shared__ __align__(16) float vw1[64], vw2[64], vwf[128], rw[128];
    __shared__ float rsm[4];

    const int tid  = threadIdx.x;
    const int b0   = blockIdx.x * 2;
    const unsigned* wsu = (const unsigned*)ws;
    const float4* Wip  = (const float4*)(ws + OFF_WI);
    const float4* Wi2p = (const float4*)(ws + OFF_WI2);

    const float bg1 = bih1[tid] + bhh1[tid];
    const float bg2 = bih2[tid] + bhh2[tid];
    const float bgd = bihd[tid] + bhhd[tid];
    float creg = 0.f;   // fp32 cell state (pointwise thread tid<256, per bb)

    // ================= Phase A: inputs, WiX =================
    if (tid < 128) lab[tid >> 6][tid & 63] = labp[(b0 + (tid >> 6)) * TENC + (tid & 63)];
    if (tid < 64)        vw1[tid]       = Vd_w[tid];
    else if (tid < 128)  vw2[tid - 64]  = Vd2_w[tid - 64];
    else if (tid < 256)  vwf[tid - 128] = V_w[tid - 128];
    else if (tid < 384)  rw[tid - 256]  = reg_w[tid - 256];
    for (int i = tid; i < 2176; i += 512) {           // xin: x[t][f], COLS skip 14
        int bb = i / 1088, r = i - bb * 1088, t = r / NF1, f = r - t * NF1;
        big[bb][XIN + r] = inq[((b0 + bb) * TENC + t) * 18 + f + (f >= 14)];
    }
    __syncthreads();
    for (int i = tid; i < 2176; i += 512) {           // WiX[f][j]
        int bb = i / 1088, r = i - bb * 1088, f = r >> 6, j = r & 63;
        float acc = Wi_b[j];
        for (int tt = 0; tt < 16; ++tt) {
            float4 w = Wip[tt * 64 + j];
            acc += big[bb][XIN + (4 * tt + 0) * NF1 + f] * w.x
                 + big[bb][XIN + (4 * tt + 1) * NF1 + f] * w.y
                 + big[bb][XIN + (4 * tt + 2) * NF1 + f] * w.z
                 + big[bb][XIN + (4 * tt + 3) * NF1 + f] * w.w;
        }
        big[bb][f * SB + j] = acc;
    }

    // ================= Phase B: encoder scan 1 =================
    {
        if (tid < 256) hcp[tid >> 7][tid & 127] = 0u;
        if (tid < 264) xhp[tid / 132][tid % 132] = 0u;
        creg = 0.f;
        unsigned wB[73];
        sfor<73>([&](auto I) { wB[I.v] = wsu[U_GB + I.v * 512 + tid]; });
        unsigned we[16];
        const int ewb = U_WE + ((tid >> 3) << 7) + ((tid & 7) << 4);
        sfor<16>([&](auto I) { we[I.v] = wsu[ewb + I.v]; });
        __syncthreads();

        for (int t = 0; t < TENC; ++t) {
            {   // e[j] for both elems, 2 chains/elem
                int j = tid >> 3, pq = tid & 7;
                float a0 = 0.f, a1 = 0.f, b0c = 0.f, b1c = 0.f;
                sfor<8>([&](auto I) {
                    a0  = fdot2p(we[I.v], hcp[0][I.v * 8 + pq], a0);
                    a1  = fdot2p(we[I.v], hcp[1][I.v * 8 + pq], a1);
                    b0c = fdot2p(we[8 + I.v], hcp[0][(8 + I.v) * 8 + pq], b0c);
                    b1c = fdot2p(we[8 + I.v], hcp[1][(8 + I.v) * 8 + pq], b1c);
                });
                float s0 = a0 + b0c, s1 = a1 + b1c;
                s0 += __shfl_xor(s0, 1, 8); s1 += __shfl_xor(s1, 1, 8);
                s0 += __shfl_xor(s0, 2, 8); s1 += __shfl_xor(s1, 2, 8);
                s0 += __shfl_xor(s0, 4, 8); s1 += __shfl_xor(s1, 4, 8);
                if (pq == 0) { ebuf[0][j] = s0; ebuf[1][j] = s1; }
            }
            __syncthreads();
            {   // block1: gates_h -> preH (dies before barrier), interleaved with score
                const uint4* h0q = (const uint4*)hcp[0];
                const uint4* h1q = (const uint4*)hcp[1];
                float q0 = 0.f, q1 = 0.f, q2 = 0.f, q3 = 0.f;
                sfor<16>([&](auto C) {
                    uint4 H0 = h0q[C.v], H1 = h1q[C.v];
                    q0 = fdot2p(wB[9 + 4 * C.v + 0], H0.x, q0);
                    q2 = fdot2p(wB[9 + 4 * C.v + 0], H1.x, q2);
                    q1 = fdot2p(wB[9 + 4 * C.v + 1], H0.y, q1);
                    q3 = fdot2p(wB[9 + 4 * C.v + 1], H1.y, q3);
                    q0 = fdot2p(wB[9 + 4 * C.v + 2], H0.z, q0);
                    q2 = fdot2p(wB[9 + 4 * C.v + 2], H1.z, q2);
                    q1 = fdot2p(wB[9 + 4 * C.v + 3], H0.w, q1);
                    q3 = fdot2p(wB[9 + 4 * C.v + 3], H1.w, q3);
                });
                preH[0][tid] = q0 + q1;
                preH[1][tid] = q2 + q3;
            }
            for (int i = tid; i < 544; i += 512) {   // score[f]: 16 threads per (bb,f)
                int bb = i / 272, r = i - bb * 272, f = r >> 4, pp = r & 15;
                float4 wx = *(const float4*)&big[bb][f * SB + pp * 4];
                float4 e4 = *(const float4*)&ebuf[bb][pp * 4];
                float4 v4 = *(const float4*)&vw1[pp * 4];
                float acc = ftanh(wx.x + e4.x) * v4.x + ftanh(wx.y + e4.y) * v4.y
                          + ftanh(wx.z + e4.z) * v4.z + ftanh(wx.w + e4.w) * v4.w;
                acc += __shfl_xor(acc, 1, 16);
                acc += __shfl_xor(acc, 2, 16);
                acc += __shfl_xor(acc, 4, 16);
                acc += __shfl_xor(acc, 8, 16);
                if (pp == 0) sc[bb][f] = acc + Vd_b[0];
            }
            __syncthreads();
            if (tid < 128) {   // softmax(17), no max pass (|s|<=4) + pack x pairs 0..8
                int bb = tid >> 6, l = tid & 63;
                float e = (l < NF1) ? __expf(sc[bb][l]) : 0.f;
                float s = e;
                for (int d = 32; d; d >>= 1) s += __shfl_xor(s, d, 64);
                float xv = (l < NF1) ? big[bb][XIN + t * NF1 + l] * (e / s) : 0.f;
                float xp = __shfl_xor(xv, 1, 64);
                if (!(l & 1) && l < 18) xhp[bb][l >> 1] = pkh_d(xv, xp);
            }
            __syncthreads();
            {   // block2: gates_x (pairs 0..8) + preH combine
                const uint4* x0q = (const uint4*)xhp[0];
                const uint4* x1q = (const uint4*)xhp[1];
                float p00 = bg1, p10 = bg1;
                sfor<2>([&](auto C) {
                    uint4 X0 = x0q[C.v], X1 = x1q[C.v];
                    p00 = fdot2p(wB[4 * C.v + 0], X0.x, p00);
                    p10 = fdot2p(wB[4 * C.v + 0], X1.x, p10);
                    p00 = fdot2p(wB[4 * C.v + 1], X0.y, p00);
                    p10 = fdot2p(wB[4 * C.v + 1], X1.y, p10);
                    p00 = fdot2p(wB[4 * C.v + 2], X0.z, p00);
                    p10 = fdot2p(wB[4 * C.v + 2], X1.z, p10);
                    p00 = fdot2p(wB[4 * C.v + 3], X0.w, p00);
                    p10 = fdot2p(wB[4 * C.v + 3], X1.w, p10);
                });
                p00 = fdot2p(wB[8], xhp[0][8], p00);
                p10 = fdot2p(wB[8], xhp[1][8], p10);
                pre[0][tid] = p00 + preH[0][tid];
                pre[1][tid] = p10 + preH[1][tid];
            }
            __syncthreads();
            if (tid < 256) {   // LSTM pointwise
                int bb = tid >> 7, k = tid & 127;
                float gi = pre[bb][k], gf = pre[bb][128 + k], gg = pre[bb][256 + k], go = pre[bb][384 + k];
                float c2 = fsig(gf) * creg + fsig(gi) * ftanh(gg);
                float h2v = fsig(go) * ftanh(c2);
                creg = c2;
                float hp = __shfl_xor(h2v, 1, 64);
                float cp = __shfl_xor(c2, 1, 64);
                if (!(k & 1)) {
                    unsigned hu = pkh_d(h2v, hp);
                    hcp[bb][k >> 1] = hu;
                    hcp[bb][64 + (k >> 1)] = pkh_d(c2, cp);
                    buf_h[bb][t][k >> 1] = hu;    // mid as f16 pair
                }
            }
            __syncthreads();
        }
    }

    // ================= Phase C: Wi2X (reads f16 mid) =================
    if (tid < 256) hcp[tid >> 7][tid & 127] = 0u;
    if (tid < 264) xhp[tid / 132][tid % 132] = 0u;
    creg = 0.f;
    for (int i = tid; i < 16512; i += 512) {
        int bb = i / 8256, r = i - bb * 8256, f = r >> 6, j = r & 63;
        float acc = Wi2_b[j];
        if (f < HH) {
            int fp = f >> 1, fh = f & 1;
            for (int tt = 0; tt < 16; ++tt) {
                float4 w = Wi2p[tt * 64 + j];
                acc += hget(buf_h[bb][4 * tt + 0][fp], fh) * w.x
                     + hget(buf_h[bb][4 * tt + 1][fp], fh) * w.y
                     + hget(buf_h[bb][4 * tt + 2][fp], fh) * w.z
                     + hget(buf_h[bb][4 * tt + 3][fp], fh) * w.w;
            }
        } else {
            for (int tt = 0; tt < 16; ++tt) {
                float4 w = Wi2p[tt * 64 + j];
                acc += lab[bb][4 * tt] * w.x + lab[bb][4 * tt + 1] * w.y
                     + lab[bb][4 * tt + 2] * w.z + lab[bb][4 * tt + 3] * w.w;
            }
        }
        big[bb][f * SB + j] = acc;
    }

    // ================= Phase D: encoder scan 2 =================
    {
        unsigned wD[129];   // pairs 0..64 = x part, 65..128 = h part
        sfor<65>([&](auto I) { wD[I.v] = wsu[U_GDX + I.v * 512 + tid]; });
        sfor<64>([&](auto I) { wD[65 + I.v] = wsu[U_GDH + I.v * 512 + tid]; });
        unsigned wes[16];
        const int ewb2 = U_WE2 + ((tid >> 3) << 7) + ((tid & 7) << 4);
        sfor<16>([&](auto I) { wes[I.v] = wsu[ewb2 + I.v]; });
        __syncthreads();

        for (int t = 0; t < TENC; ++t) {
            {   // e[j] both elems, 2 chains/elem
                int j = tid >> 3, pq = tid & 7;
                float a0 = 0.f, a1 = 0.f, b0c = 0.f, b1c = 0.f;
                sfor<8>([&](auto I) {
                    a0  = fdot2p(wes[I.v], hcp[0][I.v * 8 + pq], a0);
                    a1  = fdot2p(wes[I.v], hcp[1][I.v * 8 + pq], a1);
                    b0c = fdot2p(wes[8 + I.v], hcp[0][(8 + I.v) * 8 + pq], b0c);
                    b1c = fdot2p(wes[8 + I.v], hcp[1][(8 + I.v) * 8 + pq], b1c);
                });
                float s0 = a0 + b0c, s1 = a1 + b1c;
                s0 += __shfl_xor(s0, 1, 8); s1 += __shfl_xor(s1, 1, 8);
                s0 += __shfl_xor(s0, 2, 8); s1 += __shfl_xor(s1, 2, 8);
                s0 += __shfl_xor(s0, 4, 8); s1 += __shfl_xor(s1, 4, 8);
                if (pq == 0) { ebuf[0][j] = s0; ebuf[1][j] = s1; }
            }
            __syncthreads();
            {   // block1: gates_h -> preH (dies before barrier)
                const uint4* h0q = (const uint4*)hcp[0];
                const uint4* h1q = (const uint4*)hcp[1];
                float q0 = 0.f, q1 = 0.f, q2 = 0.f, q3 = 0.f;
                sfor<16>([&](auto C) {
                    uint4 H0 = h0q[C.v], H1 = h1q[C.v];
                    q0 = fdot2p(wD[65 + 4 * C.v + 0], H0.x, q0);
                    q2 = fdot2p(wD[65 + 4 * C.v + 0], H1.x, q2);
                    q1 = fdot2p(wD[65 + 4 * C.v + 1], H0.y, q1);
                    q3 = fdot2p(wD[65 + 4 * C.v + 1], H1.y, q3);
                    q0 = fdot2p(wD[65 + 4 * C.v + 2], H0.z, q0);
                    q2 = fdot2p(wD[65 + 4 * C.v + 2], H1.z, q2);
                    q1 = fdot2p(wD[65 + 4 * C.v + 3], H0.w, q1);
                    q3 = fdot2p(wD[65 + 4 * C.v + 3], H1.w, q3);
                });
                preH[0][tid] = q0 + q1;
                preH[1][tid] = q2 + q3;
            }
            for (int i = tid; i < 1032; i += 512) {   // score[f]: 4 threads per (bb,f)
                int bb = i / 516, r = i - bb * 516, f = r >> 2, pp = r & 3;
                float acc = 0.f;
                #pragma unroll
                for (int c = 0; c < 4; ++c) {
                    float4 wx = *(const float4*)&big[bb][f * SB + pp * 16 + c * 4];
                    float4 e4 = *(const float4*)&ebuf[bb][pp * 16 + c * 4];
                    float4 v4 = *(const float4*)&vw2[pp * 16 + c * 4];
                    acc += ftanh(wx.x + e4.x) * v4.x + ftanh(wx.y + e4.y) * v4.y
                         + ftanh(wx.z + e4.z) * v4.z + ftanh(wx.w + e4.w) * v4.w;
                }
                acc += __shfl_xor(acc, 1, 4);
                acc += __shfl_xor(acc, 2, 4);
                if (pp == 0) sc[bb][f] = acc + Vd2_b[0];
            }
            __syncthreads();
            if (tid < 128) {   // softmax(129), no max pass (|s|<=4) + pack x pairs 0..64
                int bb = tid >> 6, l = tid & 63;
                float e1 = __expf(sc[bb][l]);
                float e2 = __expf(sc[bb][l + 64]);
                float e3 = (l == 0) ? __expf(sc[bb][128]) : 0.f;
                float s = e1 + e2 + e3;
                for (int d = 32; d; d >>= 1) s += __shfl_xor(s, d, 64);
                float inv = 1.f / s;
                float v1 = hget(buf_h[bb][t][l >> 1], l & 1) * e1 * inv;
                float v2 = hget(buf_h[bb][t][32 + (l >> 1)], l & 1) * e2 * inv;
                float v1p = __shfl_xor(v1, 1, 64);
                float v2p = __shfl_xor(v2, 1, 64);
                if (!(l & 1)) {
                    xhp[bb][l >> 1] = pkh_d(v1, v1p);
                    xhp[bb][32 + (l >> 1)] = pkh_d(v2, v2p);
                }
                if (l == 0) xhp[bb][64] = pkh_d(lab[bb][t] * e3 * inv, 0.f);
            }
            __syncthreads();
            {   // block2: gates_x (pairs 0..64) + preH combine
                const uint4* x0q = (const uint4*)xhp[0];
                const uint4* x1q = (const uint4*)xhp[1];
                float p00 = bg2, p01 = 0.f, p10 = bg2, p11 = 0.f;
                sfor<16>([&](auto C) {
                    uint4 X0 = x0q[C.v], X1 = x1q[C.v];
                    p00 = fdot2p(wD[4 * C.v + 0], X0.x, p00);
                    p10 = fdot2p(wD[4 * C.v + 0], X1.x, p10);
                    p01 = fdot2p(wD[4 * C.v + 1], X0.y, p01);
                    p11 = fdot2p(wD[4 * C.v + 1], X1.y, p11);
                    p00 = fdot2p(wD[4 * C.v + 2], X0.z, p00);
                    p10 = fdot2p(wD[4 * C.v + 2], X1.z, p10);
                    p01 = fdot2p(wD[4 * C.v + 3], X0.w, p01);
                    p11 = fdot2p(wD[4 * C.v + 3], X1.w, p11);
                });
                p00 = fdot2p(wD[64], xhp[0][64], p00);
                p10 = fdot2p(wD[64], xhp[1][64], p10);
                pre[0][tid] = (p00 + p01) + preH[0][tid];
                pre[1][tid] = (p10 + p11) + preH[1][tid];
            }
            __syncthreads();
            if (tid < 256) {
                int bb = tid >> 7, k = tid & 127;
                float gi = pre[bb][k], gf = pre[bb][128 + k], gg = pre[bb][256 + k], go = pre[bb][384 + k];
                float c2 = fsig(gf) * creg + fsig(gi) * ftanh(gg);
                float h2v = fsig(go) * ftanh(c2);
                creg = c2;
                float hp = __shfl_xor(h2v, 1, 64);
                float cp = __shfl_xor(c2, 1, 64);
                if (!(k & 1)) {
                    unsigned hu = pkh_d(h2v, hp);
                    hcp[bb][k >> 1] = hu;
                    hcp[bb][64 + (k >> 1)] = pkh_d(c2, cp);
                    buf_h[bb][t][k >> 1] = hu;    // final overwrites consumed mid row
                }
            }
            __syncthreads();
        }
    }

    // ================= Phase E: WxF via f16 fdot2 (b128 broadcast reads) =================
    if (tid < 256) hcp[tid >> 7][tid & 127] = 0u;
    if (tid < 264) xhp[tid / 132][tid % 132] = 0u;
    creg = 0.f;
    {
        const int j = tid & 127;
        unsigned wxh[64];
        sfor<64>([&](auto I) { wxh[I.v] = wsu[U_WXH + I.v * 128 + j]; });
        for (int u = tid >> 7; u < 128; u += 4) {
            int bb = u >> 6, tt = u & 63;
            const uint4* bq = (const uint4*)buf_h[bb][tt];
            float a0 = Wx_b[j], a1 = 0.f, a2 = 0.f, a3 = 0.f;
            sfor<16>([&](auto C) {
                uint4 X = bq[C.v];
                a0 = fdot2p(wxh[4 * C.v + 0], X.x, a0);
                a1 = fdot2p(wxh[4 * C.v + 1], X.y, a1);
                a2 = fdot2p(wxh[4 * C.v + 2], X.z, a2);
                a3 = fdot2p(wxh[4 * C.v + 3], X.w, a3);
            });
            big[bb][tt * SWF + j] = (a0 + a1) + (a2 + a3);
        }
    }

    // ================= Phase F: decoder =================
    {
        unsigned wF[128];   // pairs 0..63 = din part, 64..127 = h part
        sfor<64>([&](auto I) { wF[I.v] = wsu[U_GFX + I.v * 512 + tid]; });
        sfor<64>([&](auto I) { wF[64 + I.v] = wsu[U_GFH + I.v * 512 + tid]; });
        unsigned wh[32];
        const int whb = U_WH + ((tid >> 2) << 7) + ((tid & 3) << 5);
        sfor<32>([&](auto I) { wh[I.v] = wsu[whb + I.v]; });
        __syncthreads();

        for (int n = 0; n < NDEC; ++n) {
            {   // e[j] both elems, 2 chains/elem
                int j = tid >> 2, pq = tid & 3;
                float a0 = 0.f, a1 = 0.f, b0c = 0.f, b1c = 0.f;
                sfor<16>([&](auto I) {
                    a0  = fdot2p(wh[I.v], hcp[0][I.v * 4 + pq], a0);
                    a1  = fdot2p(wh[I.v], hcp[1][I.v * 4 + pq], a1);
                    b0c = fdot2p(wh[16 + I.v], hcp[0][(16 + I.v) * 4 + pq], b0c);
                    b1c = fdot2p(wh[16 + I.v], hcp[1][(16 + I.v) * 4 + pq], b1c);
                });
                float s0 = a0 + b0c, s1 = a1 + b1c;
                s0 += __shfl_xor(s0, 1, 4); s1 += __shfl_xor(s1, 1, 4);
                s0 += __shfl_xor(s0, 2, 4); s1 += __shfl_xor(s1, 2, 4);
                if (pq == 0) { ebuf[0][j] = s0; ebuf[1][j] = s1; }
            }
            __syncthreads();
            {   // block1: gates_h -> preH (dies before barrier)
                const uint4* h0q = (const uint4*)hcp[0];
                const uint4* h1q = (const uint4*)hcp[1];
                float q0 = 0.f, q1 = 0.f, q2 = 0.f, q3 = 0.f;
                sfor<16>([&](auto C) {
                    uint4 H0 = h0q[C.v], H1 = h1q[C.v];
                    q0 = fdot2p(wF[64 + 4 * C.v + 0], H0.x, q0);
                    q2 = fdot2p(wF[64 + 4 * C.v + 0], H1.x, q2);
                    q1 = fdot2p(wF[64 + 4 * C.v + 1], H0.y, q1);
                    q3 = fdot2p(wF[64 + 4 * C.v + 1], H1.y, q3);
                    q0 = fdot2p(wF[64 + 4 * C.v + 2], H0.z, q0);
                    q2 = fdot2p(wF[64 + 4 * C.v + 2], H1.z, q2);
                    q1 = fdot2p(wF[64 + 4 * C.v + 3], H0.w, q1);
                    q3 = fdot2p(wF[64 + 4 * C.v + 3], H1.w, q3);
                });
                preH[0][tid] = q0 + q1;
                preH[1][tid] = q2 + q3;
            }
            for (int i = tid; i < 1024; i += 512) {   // s[tt]: 8 threads per (bb,tt)
                int bb = i >> 9, r = i & 511, tt = r >> 3, pp = r & 7;
                float acc = 0.f;
                #pragma unroll
                for (int c = 0; c < 4; ++c) {
                    float4 wx = *(const float4*)&big[bb][tt * SWF + pp * 16 + c * 4];
                    float4 e4 = *(const float4*)&ebuf[bb][pp * 16 + c * 4];
                    float4 v4 = *(const float4*)&vwf[pp * 16 + c * 4];
                    acc += ftanh(wx.x + e4.x) * v4.x + ftanh(wx.y + e4.y) * v4.y
                         + ftanh(wx.z + e4.z) * v4.z + ftanh(wx.w + e4.w) * v4.w;
                }
                acc += __shfl_xor(acc, 1, 8);
                acc += __shfl_xor(acc, 2, 8);
                acc += __shfl_xor(acc, 4, 8);
                if (pp == 0) sc[bb][tt] = acc + V_b[0];
            }
            __syncthreads();
            if (tid < 128) {   // softmax(64) over time, no max pass (|s|<=8)
                int bb = tid >> 6, l = tid & 63;
                float e = __expf(sc[bb][l]);
                float s = e;
                for (int d = 32; d; d >>= 1) s += __shfl_xor(s, d, 64);
                att[bb][l] = e / s;
            }
            __syncthreads();
            for (int i = tid; i < 1024; i += 512) {   // din[k], pack pairs 0..63
                int bb = i >> 9, r = i & 511, k = r >> 2, pq = r & 3;
                int kp = k >> 1, kh = k & 1;
                float acc = 0.f;
                #pragma unroll
                for (int u = 0; u < 16; ++u) {
                    int tt = u * 4 + pq;
                    acc += att[bb][tt] * hget(buf_h[bb][tt][kp], kh);
                }
                acc += __shfl_xor(acc, 1, 64);
                acc += __shfl_xor(acc, 2, 64);
                float dp = __shfl_xor(acc, 4, 64);
                if ((r & 7) == 0) xhp[bb][r >> 3] = pkh_d(acc, dp);
            }
            __syncthreads();
            {   // block2: gates_x (din pairs 0..63) + preH combine
                const uint4* x0q = (const uint4*)xhp[0];
                const uint4* x1q = (const uint4*)xhp[1];
                float p00 = bgd, p01 = 0.f, p10 = bgd, p11 = 0.f;
                sfor<16>([&](auto C) {
                    uint4 X0 = x0q[C.v], X1 = x1q[C.v];
                    p00 = fdot2p(wF[4 * C.v + 0], X0.x, p00);
                    p10 = fdot2p(wF[4 * C.v + 0], X1.x, p10);
                    p01 = fdot2p(wF[4 * C.v + 1], X0.y, p01);
                    p11 = fdot2p(wF[4 * C.v + 1], X1.y, p11);
                    p00 = fdot2p(wF[4 * C.v + 2], X0.z, p00);
                    p10 = fdot2p(wF[4 * C.v + 2], X1.z, p10);
                    p01 = fdot2p(wF[4 * C.v + 3], X0.w, p01);
                    p11 = fdot2p(wF[4 * C.v + 3], X1.w, p11);
                });
                pre[0][tid] = (p00 + p01) + preH[0][tid];
                pre[1][tid] = (p10 + p11) + preH[1][tid];
            }
            __syncthreads();
            if (tid < 256) {   // pointwise + fused output partial
                int bb = tid >> 7, k = tid & 127;
                float gi = pre[bb][k], gf = pre[bb][128 + k], gg = pre[bb][256 + k], go = pre[bb][384 + k];
                float c2 = fsig(gf) * creg + fsig(gi) * ftanh(gg);
                float h2v = fsig(go) * ftanh(c2);
                creg = c2;
                float hp = __shfl_xor(h2v, 1, 64);
                float cp = __shfl_xor(c2, 1, 64);
                if (!(k & 1)) {
                    unsigned hu = pkh_d(h2v, hp);
                    hcp[bb][k >> 1] = hu;
                    hcp[bb][64 + (k >> 1)] = pkh_d(c2, cp);
                }
                if (n >= 6) {
                    float v = h2v * rw[k];
                    for (int d = 32; d; d >>= 1) v += __shfl_xor(v, d, 64);
                    if ((tid & 63) == 0) rsm[tid >> 6] = v;
                }
            }
            __syncthreads();
            if (n >= 6 && tid < 2)
                out[(b0 + tid) * TDEC + (n - 6)] = rsm[tid * 2] + rsm[tid * 2 + 1] + reg_b[0];
        }
    }
}

extern "C" void kernel_launch(void* const* d_in, const int* in_sizes, int n_in,
                              void* d_out, int out_size, void* d_ws, size_t ws_size,
                              hipStream_t stream)
{
    const float* inq   = (const float*)d_in[0];
    const float* labp  = (const float*)d_in[1];
    const float* Wih1  = (const float*)d_in[2];
    const float* Whh1  = (const float*)d_in[3];
    const float* bih1  = (const float*)d_in[4];
    const float* bhh1  = (const float*)d_in[5];
    const float* Wih2  = (const float*)d_in[6];
    const float* Whh2  = (const float*)d_in[7];
    const float* bih2  = (const float*)d_in[8];
    const float* bhh2  = (const float*)d_in[9];
    const float* Wihd  = (const float*)d_in[10];
    const float* Whhd  = (const float*)d_in[11];
    const float* bihd  = (const float*)d_in[12];
    const float* bhhd  = (const float*)d_in[13];
    const float* Wi_w  = (const float*)d_in[14];
    const float* Wi_b  = (const float*)d_in[15];
    const float* We_w  = (const float*)d_in[16];
    const float* Vd_w  = (const float*)d_in[17];
    const float* Vd_b  = (const float*)d_in[18];
    const float* Wi2_w = (const float*)d_in[19];
    const float* Wi2_b = (const float*)d_in[20];
    const float* We2_w = (const float*)d_in[21];
    const float* Vd2_w = (const float*)d_in[22];
    const float* Vd2_b = (const float*)d_in[23];
    const float* Wx_w  = (const float*)d_in[24];
    const float* Wx_b  = (const float*)d_in[25];
    const float* Wh_w  = (const float*)d_in[26];
    const float* V_w   = (const float*)d_in[27];
    const float* V_b   = (const float*)d_in[28];
    const float* reg_w = (const float*)d_in[29];
    const float* reg_b = (const float*)d_in[30];
    float* ws  = (float*)d_ws;
    unsigned* wsu = (unsigned*)d_ws;
    float* out = (float*)d_out;

    pack_f2<<<dim3(16, 2), 256, 0, stream>>>(Wi_w, Wi2_w, ws);
    pack_gp<<<73, 512, 0, stream>>>(Wih1, Whh1, 17, 18, 0, U_GB, 512, wsu);
    pack_gp<<<65, 512, 0, stream>>>(Wih2, Whh2, 129, 130, 0, U_GDX, 512, wsu);
    pack_gp<<<64, 512, 0, stream>>>(Wih2, Whh2, 129, 130, 65, U_GDH, 512, wsu);
    pack_gp<<<64, 512, 0, stream>>>(Wihd, Whhd, 128, 128, 0, U_GFX, 512, wsu);
    pack_gp<<<64, 512, 0, stream>>>(Wihd, Whhd, 128, 128, 64, U_GFH, 512, wsu);
    pack_gp<<<64, 128, 0, stream>>>(Wx_w, Wx_w, 128, 128, 0, U_WXH, 128, wsu);
    pack_ew<<<8, 1024, 0, stream>>>(We_w, 64, 8, 16, U_WE, wsu);
    pack_ew<<<8, 1024, 0, stream>>>(We2_w, 64, 8, 16, U_WE2, wsu);
    pack_ew<<<16, 1024, 0, stream>>>(Wh_w, 128, 4, 32, U_WH, wsu);
    dstp_main<<<256, 512, 0, stream>>>(inq, labp, bih1, bhh1, bih2, bhh2, bihd, bhhd,
                                       Wi_b, Vd_w, Vd_b, Wi2_b, Vd2_w, Vd2_b,
                                       Wx_b, V_w, V_b, reg_w, reg_b, ws, out);
}